// Round 7
// baseline (523.158 us; speedup 1.0000x reference)
//
#include <hip/hip_runtime.h>
#include <math.h>

// EmbeddingEncoder: B=128, S=384, D=96, H=4, K=7, L=4.
// Round 6: zero-barrier attention. K/V MFMA B-fragments read directly from global
// (L2/L1-served); Q/P cross-lane staging via wave-private LDS (no __syncthreads).
// WO stays folded into V (WVO), one proj dispatch, one attention dispatch.

constexpr int B = 128;
constexpr int S = 384;
constexpr int D = 96;
constexpr int H = 4;
constexpr int KW = 7;
constexpr int L = 4;
constexpr int ROWS = B * S;                      // 49152
constexpr long long NTOT = (long long)ROWS * D;  // 4718592 (== ROWS*96)
constexpr float SQRTD = 9.797958971132712f;

typedef _Float16 f16x8 __attribute__((ext_vector_type(8)));
typedef float f32x4 __attribute__((ext_vector_type(4)));
typedef unsigned short us;
typedef unsigned short us8 __attribute__((ext_vector_type(8)));
typedef unsigned short us4 __attribute__((ext_vector_type(4)));

__device__ __forceinline__ us f2h(float f) {
    _Float16 h = (_Float16)f;
    return __builtin_bit_cast(us, h);
}
__device__ __forceinline__ f16x8 ldh(const us* p) {
    return *reinterpret_cast<const f16x8*>(p);
}

// ---------------- positional encoding ----------------
__global__ void pe_kernel(float* __restrict__ pe) {
    int idx = blockIdx.x * 256 + threadIdx.x;
    if (idx >= S * D) return;
    int s = idx / D, c = idx - s * D;
    int j = c >> 1;
    float expo = (c & 1) ? (4.0f * j + 2.0f) / 96.0f : (4.0f * j) / 96.0f;
    float freq = expf(-expo * logf(10000.0f));
    float ang = (float)s * freq;
    pe[idx] = (c & 1) ? cosf(ang) : sinf(ang);
}

// ---------------- embed ----------------
__global__ void embed_kernel(const float* __restrict__ in, const float* __restrict__ pe,
                             float* __restrict__ x) {
    long long idx = (long long)blockIdx.x * 256 + threadIdx.x;
    if (idx >= NTOT) return;
    x[idx] = in[idx] * SQRTD + pe[idx % (S * D)];
}

// ---------------- weight prep (f16, transposed; sqrt(D) folded into Wq) ----------------
__global__ void prep_w(const float* __restrict__ WQ, const float* __restrict__ WK,
                       const float* __restrict__ cpw, const float* __restrict__ w1,
                       const float* __restrict__ w2,
                       us* __restrict__ wqT, us* __restrict__ wkT, us* __restrict__ pw16,
                       us* __restrict__ w1T, us* __restrict__ w2Tp) {
    int idx = blockIdx.x * 256 + threadIdx.x;
    if (idx >= H * D * D) return;  // 36864
    int h = idx / (D * D), rem = idx - h * (D * D);
    int d = rem / D, e = rem - d * D;
    int t = h * D * D + e * D + d;
    wqT[t] = f2h(WQ[idx] * SQRTD);
    wkT[t] = f2h(WK[idx]);
    pw16[idx] = f2h(cpw[idx]);  // L*D*D == 36864
    if (idx < 48 * 96) {
        int m = idx / 96, c = idx - m * 96;
        w1T[idx] = f2h(w1[c * 48 + m]);
    }
    if (idx < 96 * 64) {
        int o = idx / 64, m = idx - o * 64;
        w2Tp[idx] = (m < 48) ? f2h(w2[m * 96 + o]) : (us)0;
    }
}

// ---------------- WVO_h = WV_h @ WO_h, stored transposed [h][o][d] (f32 compute) ----------------
__global__ void prep_wvo(const float* __restrict__ WV, const float* __restrict__ WO,
                         us* __restrict__ wvoT) {
    int blk = blockIdx.x;  // 24 = H * 6
    int h = blk / 6, ot = blk - h * 6;
    int tid = threadIdx.x;
    const float* wv = WV + (size_t)h * D * D;  // [d][e]
    const float* wo = WO + (size_t)h * D * D;  // rows e, cols o
    for (int i = tid; i < 16 * 96; i += 256) {
        int o = ot * 16 + i / 96, d = i - (i / 96) * 96;
        float acc = 0.f;
        for (int e = 0; e < 96; e++) acc += wv[d * 96 + e] * wo[e * 96 + o];
        wvoT[(size_t)h * D * D + o * 96 + d] = f2h(acc);
    }
}

// ---------------- layernorm -> f16 ----------------
__global__ void ln16h_kernel(const float* __restrict__ x, const float* __restrict__ gln,
                             const float* __restrict__ bln, us* __restrict__ out) {
    int wave = threadIdx.x >> 6;
    int lane = threadIdx.x & 63;
    int row = blockIdx.x * 4 + wave;
    if (row >= ROWS) return;
    const float* p = x + (size_t)row * D;
    float v0 = p[lane];
    float v1 = (lane < 32) ? p[lane + 64] : 0.f;
    float sm = v0 + v1, q = v0 * v0 + v1 * v1;
    for (int off = 32; off > 0; off >>= 1) {
        sm += __shfl_xor(sm, off);
        q += __shfl_xor(q, off);
    }
    float mean = sm * (1.0f / D);
    float var = q * (1.0f / D) - mean * mean;
    float rstd = rsqrtf(var + 1e-5f);
    us* o = out + (size_t)row * D;
    o[lane] = f2h((v0 - mean) * rstd * gln[lane] + bln[lane]);
    if (lane < 32) o[lane + 64] = f2h((v1 - mean) * rstd * gln[lane + 64] + bln[lane + 64]);
}

// ---------------- fused conv block: LN(+halo) -> dw -> pw MFMA -> xout = xin + relu ----------------
__global__ void conv_fused(const float* __restrict__ xin, float* __restrict__ xout,
                           const float* __restrict__ gln, const float* __restrict__ bln,
                           const float* __restrict__ dwW, const float* __restrict__ dwB,
                           const us* __restrict__ pwW, const float* __restrict__ pwb) {
    __shared__ us lnb[70 * 104];
    __shared__ us dwb[64 * 104];
    __shared__ float lw[96 * 8];
    int tid = threadIdx.x;
    int wave = tid >> 6, lane = tid & 63;
    int r0 = blockIdx.x * 64;
    int b = r0 / S, s0 = r0 % S;

    for (int i = tid; i < 96 * KW; i += 256) lw[(i / KW) * 8 + (i % KW)] = dwW[i];

    for (int i = wave; i < 70; i += 4) {
        int s = s0 - 3 + i;
        bool valid = (unsigned)s < (unsigned)S;
        float v0 = 0.f, v1 = 0.f;
        const float* p = xin + ((size_t)b * S + s) * 96;
        if (valid) {
            v0 = p[lane];
            v1 = (lane < 32) ? p[lane + 64] : 0.f;
        }
        float sm = v0 + v1, q = v0 * v0 + v1 * v1;
        for (int off = 32; off > 0; off >>= 1) {
            sm += __shfl_xor(sm, off);
            q += __shfl_xor(q, off);
        }
        float mean = sm * (1.0f / D);
        float var = q * (1.0f / D) - mean * mean;
        float rstd = rsqrtf(var + 1e-5f);
        lnb[i * 104 + lane] = f2h(valid ? (v0 - mean) * rstd * gln[lane] + bln[lane] : 0.f);
        if (lane < 32)
            lnb[i * 104 + 64 + lane] =
                f2h(valid ? (v1 - mean) * rstd * gln[lane + 64] + bln[lane + 64] : 0.f);
    }
    __syncthreads();

    for (int u = tid; u < 768; u += 256) {
        int j = u / 12, c0 = (u - (u / 12) * 12) * 8;
        float acc[8];
        #pragma unroll
        for (int j2 = 0; j2 < 8; j2++) acc[j2] = dwB[c0 + j2];
        #pragma unroll
        for (int k = 0; k < KW; k++) {
            f16x8 v = ldh(&lnb[(j + k) * 104 + c0]);
            #pragma unroll
            for (int j2 = 0; j2 < 8; j2++) acc[j2] += (float)v[j2] * lw[(c0 + j2) * 8 + k];
        }
        us8 o;
        #pragma unroll
        for (int j2 = 0; j2 < 8; j2++) o[j2] = f2h(acc[j2]);
        *reinterpret_cast<us8*>(&dwb[j * 104 + c0]) = o;
    }
    __syncthreads();

    int lmod = lane & 15, ldiv = lane >> 4, m0 = wave * 16;
    f32x4 acc[6] = {};
    #pragma unroll
    for (int kk = 0; kk < 3; kk++) {
        f16x8 af = ldh(&dwb[(m0 + lmod) * 104 + kk * 32 + ldiv * 8]);
        #pragma unroll
        for (int n = 0; n < 6; n++) {
            f16x8 bf = ldh(pwW + (size_t)(n * 16 + lmod) * 96 + kk * 32 + ldiv * 8);
            acc[n] = __builtin_amdgcn_mfma_f32_16x16x32_f16(af, bf, acc[n], 0, 0, 0);
        }
    }
    #pragma unroll
    for (int n = 0; n < 6; n++) {
        int o = n * 16 + lmod;
        float bv = pwb[o];
        #pragma unroll
        for (int r = 0; r < 4; r++) {
            size_t row = (size_t)r0 + m0 + ldiv * 4 + r;
            xout[row * 96 + o] = xin[row * 96 + o] + fmaxf(acc[n][r] + bv, 0.f);
        }
    }
}

// ---------------- K / V' projection, all heads in one dispatch ----------------
__global__ void proj_all(const us* __restrict__ h16, const us* __restrict__ wkT,
                         const us* __restrict__ wvoT, us* __restrict__ Kall,
                         us* __restrict__ Vall) {
    int hd = blockIdx.y >> 1, type = blockIdx.y & 1;
    const us* W = (type ? wvoT : wkT) + (size_t)hd * D * D;
    int tid = threadIdx.x;
    int wave = tid >> 6, lane = tid & 63, lmod = lane & 15, ldiv = lane >> 4;
    int row0 = blockIdx.x * 64, m0 = wave * 16;
    f32x4 acc[6] = {};
    #pragma unroll
    for (int kk = 0; kk < 3; kk++) {
        f16x8 af = ldh(h16 + (size_t)(row0 + m0 + lmod) * 96 + kk * 32 + ldiv * 8);
        #pragma unroll
        for (int n = 0; n < 6; n++) {
            f16x8 bf = ldh(W + (size_t)(n * 16 + lmod) * 96 + kk * 32 + ldiv * 8);
            acc[n] = __builtin_amdgcn_mfma_f32_16x16x32_f16(af, bf, acc[n], 0, 0, 0);
        }
    }
    if (!type) {
        us* Kf = Kall + (size_t)hd * NTOT;
        #pragma unroll
        for (int n = 0; n < 6; n++)
            #pragma unroll
            for (int r = 0; r < 4; r++)
                Kf[(size_t)(row0 + m0 + ldiv * 4 + r) * 96 + n * 16 + lmod] = f2h(acc[n][r]);
    } else {
        us* Vt = Vall + (size_t)hd * NTOT;
        int b = row0 / S;
        int sb = row0 % S + m0 + ldiv * 4;
        #pragma unroll
        for (int n = 0; n < 6; n++) {
            us4 pk;
            #pragma unroll
            for (int r = 0; r < 4; r++) pk[r] = f2h(acc[n][r]);
            *reinterpret_cast<us4*>(Vt + ((size_t)b * 96 + n * 16 + lmod) * S + sb) = pk;
        }
    }
}

// ---------------- zero-barrier attention: x += sum_h softmax(QK^T) @ V'_h ----------------
// grid 768 (XCD-swizzled), 4 waves/block; each wave owns 16 q-rows, no __syncthreads.
__global__ __launch_bounds__(256, 2) void attn_nb(const us* __restrict__ h16,
                                                  const us* __restrict__ wqT,
                                                  const us* __restrict__ Kall,
                                                  const us* __restrict__ Vall,
                                                  float* __restrict__ x) {
    __shared__ us qb[4][2][16 * 104];  // per-wave Q staging, double-buffered over head parity
    __shared__ us sP[4][2][16 * 72];   // per-wave P staging, double-buffered over chunk parity
    int tid = threadIdx.x, wave = tid >> 6, lane = tid & 63;
    int lmod = lane & 15, ldiv = lane >> 4;
    int p = blockIdx.x;
    int gl = (p & 7) * 96 + (p >> 3);  // XCD-chunked swizzle (768 = 8*96)
    int b = gl / 6, q0 = (gl % 6) * 64;
    size_t rowbase = (size_t)b * S + q0 + wave * 16;  // this wave's 16 rows

    f32x4 oacc[6] = {};

    for (int hd = 0; hd < H; hd++) {
        const us* wq = wqT + (size_t)hd * D * D;
        const us* Kh = Kall + (size_t)hd * NTOT + (size_t)b * S * 96;
        const us* Vh = Vall + (size_t)hd * NTOT + (size_t)b * 96 * S;

        // Q projection (sqrt(D) pre-folded); C-layout -> wave-private LDS -> A-frags
        f32x4 qa[6] = {};
        #pragma unroll
        for (int kk = 0; kk < 3; kk++) {
            f16x8 af = ldh(h16 + (rowbase + lmod) * 96 + kk * 32 + ldiv * 8);
            #pragma unroll
            for (int n = 0; n < 6; n++) {
                f16x8 bf = ldh(wq + (size_t)(n * 16 + lmod) * 96 + kk * 32 + ldiv * 8);
                qa[n] = __builtin_amdgcn_mfma_f32_16x16x32_f16(af, bf, qa[n], 0, 0, 0);
            }
        }
        us* qw = qb[wave][hd & 1];
        #pragma unroll
        for (int n = 0; n < 6; n++)
            #pragma unroll
            for (int r = 0; r < 4; r++)
                qw[(ldiv * 4 + r) * 104 + n * 16 + lmod] = f2h(qa[n][r]);
        f16x8 aq[3];
        #pragma unroll
        for (int kk = 0; kk < 3; kk++) aq[kk] = ldh(&qw[lmod * 104 + kk * 32 + ldiv * 8]);

        // scores = Q @ K^T, B-frags direct from global (row-major K matches frag layout)
        f32x4 sc[24] = {};
        #pragma unroll
        for (int c = 0; c < 6; c++)
            #pragma unroll
            for (int nt = 0; nt < 4; nt++)
                #pragma unroll
                for (int kk = 0; kk < 3; kk++) {
                    f16x8 bf =
                        ldh(Kh + (size_t)(c * 64 + nt * 16 + lmod) * 96 + kk * 32 + ldiv * 8);
                    sc[c * 4 + nt] =
                        __builtin_amdgcn_mfma_f32_16x16x32_f16(aq[kk], bf, sc[c * 4 + nt], 0, 0, 0);
                }

        // in-register softmax (rows of this lane: ldiv*4 + r)
        #pragma unroll
        for (int r = 0; r < 4; r++) {
            float m = -1e30f;
            #pragma unroll
            for (int t = 0; t < 24; t++) m = fmaxf(m, sc[t][r]);
            m = fmaxf(m, __shfl_xor(m, 1));
            m = fmaxf(m, __shfl_xor(m, 2));
            m = fmaxf(m, __shfl_xor(m, 4));
            m = fmaxf(m, __shfl_xor(m, 8));
            float sum = 0.f;
            #pragma unroll
            for (int t = 0; t < 24; t++) {
                float pv = __expf(sc[t][r] - m);
                sc[t][r] = pv;
                sum += pv;
            }
            sum += __shfl_xor(sum, 1);
            sum += __shfl_xor(sum, 2);
            sum += __shfl_xor(sum, 4);
            sum += __shfl_xor(sum, 8);
            float inv = 1.f / sum;
            #pragma unroll
            for (int t = 0; t < 24; t++) sc[t][r] *= inv;
        }

        // oacc += P @ V'; P via wave-private LDS, V' B-frags direct from global
        #pragma unroll
        for (int c = 0; c < 6; c++) {
            us* pw = sP[wave][c & 1];
            #pragma unroll
            for (int nt = 0; nt < 4; nt++)
                #pragma unroll
                for (int r = 0; r < 4; r++)
                    pw[(ldiv * 4 + r) * 72 + nt * 16 + lmod] = f2h(sc[c * 4 + nt][r]);
            #pragma unroll
            for (int kk = 0; kk < 2; kk++) {
                f16x8 pf = ldh(&pw[lmod * 72 + kk * 32 + ldiv * 8]);
                #pragma unroll
                for (int n = 0; n < 6; n++) {
                    f16x8 bf = ldh(Vh + (size_t)(n * 16 + lmod) * S + c * 64 + kk * 32 + ldiv * 8);
                    oacc[n] = __builtin_amdgcn_mfma_f32_16x16x32_f16(pf, bf, oacc[n], 0, 0, 0);
                }
            }
        }
    }

    // single residual write
    #pragma unroll
    for (int n = 0; n < 6; n++)
        #pragma unroll
        for (int r = 0; r < 4; r++)
            x[(rowbase + ldiv * 4 + r) * 96 + n * 16 + lmod] += oacc[n][r];
}

// ---------------- fused LN + FFN: out = x + sigmoid(LN(x)@w1+b1)@w2+b2 ----------------
__global__ void ffn_ln(const float* __restrict__ x, const float* __restrict__ gln,
                       const float* __restrict__ bln, const us* __restrict__ w1T,
                       const float* __restrict__ b1, const us* __restrict__ w2Tp,
                       const float* __restrict__ b2, float* __restrict__ out) {
    __shared__ us lnb[64 * 104];
    __shared__ us mid[64 * 72];
    int tid = threadIdx.x, wave = tid >> 6, lane = tid & 63;
    int lmod = lane & 15, ldiv = lane >> 4, m0 = wave * 16;
    int row0 = blockIdx.x * 64;

    for (int i = wave; i < 64; i += 4) {
        const float* p = x + (size_t)(row0 + i) * 96;
        float v0 = p[lane];
        float v1 = (lane < 32) ? p[lane + 64] : 0.f;
        float sm = v0 + v1, q = v0 * v0 + v1 * v1;
        for (int off = 32; off > 0; off >>= 1) {
            sm += __shfl_xor(sm, off);
            q += __shfl_xor(q, off);
        }
        float mean = sm * (1.0f / D);
        float var = q * (1.0f / D) - mean * mean;
        float rstd = rsqrtf(var + 1e-5f);
        lnb[i * 104 + lane] = f2h((v0 - mean) * rstd * gln[lane] + bln[lane]);
        if (lane < 32)
            lnb[i * 104 + 64 + lane] = f2h((v1 - mean) * rstd * gln[lane + 64] + bln[lane + 64]);
    }
    __syncthreads();

    f32x4 a3[3] = {};
    #pragma unroll
    for (int kk = 0; kk < 3; kk++) {
        f16x8 af = ldh(&lnb[(m0 + lmod) * 104 + kk * 32 + ldiv * 8]);
        #pragma unroll
        for (int n = 0; n < 3; n++) {
            f16x8 bf = ldh(w1T + (size_t)(n * 16 + lmod) * 96 + kk * 32 + ldiv * 8);
            a3[n] = __builtin_amdgcn_mfma_f32_16x16x32_f16(af, bf, a3[n], 0, 0, 0);
        }
    }
    #pragma unroll
    for (int n = 0; n < 3; n++) {
        float bv = b1[n * 16 + lmod];
        #pragma unroll
        for (int r = 0; r < 4; r++) {
            float v = a3[n][r] + bv;
            mid[(m0 + ldiv * 4 + r) * 72 + n * 16 + lmod] = f2h(1.f / (1.f + __expf(-v)));
        }
    }
    #pragma unroll
    for (int r = 0; r < 4; r++) mid[(m0 + ldiv * 4 + r) * 72 + 48 + lmod] = 0;
    __syncthreads();

    f32x4 a6[6] = {};
    #pragma unroll
    for (int kk = 0; kk < 2; kk++) {
        f16x8 af = ldh(&mid[(m0 + lmod) * 72 + kk * 32 + ldiv * 8]);
        #pragma unroll
        for (int n = 0; n < 6; n++) {
            f16x8 bf = ldh(w2Tp + (size_t)(n * 16 + lmod) * 64 + kk * 32 + ldiv * 8);
            a6[n] = __builtin_amdgcn_mfma_f32_16x16x32_f16(af, bf, a6[n], 0, 0, 0);
        }
    }
    #pragma unroll
    for (int n = 0; n < 6; n++) {
        int o = n * 16 + lmod;
        float bv = b2[o];
        #pragma unroll
        for (int r = 0; r < 4; r++) {
            size_t row = (size_t)row0 + m0 + ldiv * 4 + r;
            out[row * 96 + o] = x[row * 96 + o] + a6[n][r] + bv;
        }
    }
}

extern "C" void kernel_launch(void* const* d_in, const int* in_sizes, int n_in,
                              void* d_out, int out_size, void* d_ws, size_t ws_size,
                              hipStream_t stream) {
    const float* in   = (const float*)d_in[0];
    const float* cdw  = (const float*)d_in[2];
    const float* cdwb = (const float*)d_in[3];
    const float* cpw  = (const float*)d_in[4];
    const float* cpwb = (const float*)d_in[5];
    const float* WQ   = (const float*)d_in[6];
    const float* WK   = (const float*)d_in[7];
    const float* WV   = (const float*)d_in[8];
    const float* WO   = (const float*)d_in[9];
    const float* w1   = (const float*)d_in[10];
    const float* b1   = (const float*)d_in[11];
    const float* w2   = (const float*)d_in[12];
    const float* b2   = (const float*)d_in[13];
    const float* lng  = (const float*)d_in[14];
    const float* lnb  = (const float*)d_in[15];
    float* out = (float*)d_out;
    float* ws = (float*)d_ws;

    float* x   = ws;
    float* pe  = x + NTOT;
    float* x2  = pe + S * D;
    us* h16    = (us*)(x2 + NTOT);
    us* Kall   = h16 + NTOT;               // [H][ROWS][96]
    us* Vall   = Kall + (size_t)H * NTOT;  // [H][B][96][S]
    us* wqT    = Vall + (size_t)H * NTOT;
    us* wkT    = wqT + H * D * D;
    us* wvoT   = wkT + H * D * D;
    us* pw16   = wvoT + H * D * D;
    us* w1T    = pw16 + L * D * D;
    us* w2Tp   = w1T + 48 * 96;
    // total ~= 123 MB

    pe_kernel<<<(S * D + 255) / 256, 256, 0, stream>>>(pe);
    embed_kernel<<<(int)(NTOT / 256), 256, 0, stream>>>(in, pe, x);
    prep_w<<<(H * D * D + 255) / 256, 256, 0, stream>>>(WQ, WK, cpw, w1, w2,
                                                        wqT, wkT, pw16, w1T, w2Tp);
    prep_wvo<<<H * 6, 256, 0, stream>>>(WV, WO, wvoT);

    for (int i = 0; i < L; i++) {
        const float* xi = (i & 1) ? x2 : x;
        float* xo = (i & 1) ? x : x2;
        conv_fused<<<ROWS / 64, 256, 0, stream>>>(xi, xo, lng + i * D, lnb + i * D,
                                                  cdw + i * D * KW, cdwb + i * D,
                                                  pw16 + i * D * D, cpwb + i * D);
    }
    // L=4 even -> result back in x

    ln16h_kernel<<<ROWS / 4, 256, 0, stream>>>(x, lng + L * D, lnb + L * D, h16);
    proj_all<<<dim3(ROWS / 64, 2 * H), 256, 0, stream>>>(h16, wkT, wvoT, Kall, Vall);
    attn_nb<<<ROWS / 64, 256, 0, stream>>>(h16, wqT, Kall, Vall, x);

    ffn_ln<<<ROWS / 64, 256, 0, stream>>>(x, lng + (L + 1) * D, lnb + (L + 1) * D,
                                          w1T, b1, w2Tp, b2, out);
}

// Round 8
// 403.766 us; speedup vs baseline: 1.2957x; 1.2957x over previous
//
#include <hip/hip_runtime.h>
#include <math.h>

// EmbeddingEncoder: B=128, S=384, D=96, H=4, K=7, L=4.
// Round 7: zero-barrier attention with K/V/Wq pre-swizzled into MFMA B-fragment
// order in global memory (coalesced lane*8 loads, L1-shared across waves).
// proj repacks via LDS; attention has no __syncthreads and no gathers.

constexpr int B = 128;
constexpr int S = 384;
constexpr int D = 96;
constexpr int H = 4;
constexpr int KW = 7;
constexpr int L = 4;
constexpr int ROWS = B * S;                      // 49152
constexpr long long NTOT = (long long)ROWS * D;  // 4718592
constexpr float SQRTD = 9.797958971132712f;

typedef _Float16 f16x8 __attribute__((ext_vector_type(8)));
typedef float f32x4 __attribute__((ext_vector_type(4)));
typedef unsigned short us;
typedef unsigned short us8 __attribute__((ext_vector_type(8)));

__device__ __forceinline__ us f2h(float f) {
    _Float16 h = (_Float16)f;
    return __builtin_bit_cast(us, h);
}
__device__ __forceinline__ f16x8 ldh(const us* p) {
    return *reinterpret_cast<const f16x8*>(p);
}

// ---------------- positional encoding ----------------
__global__ void pe_kernel(float* __restrict__ pe) {
    int idx = blockIdx.x * 256 + threadIdx.x;
    if (idx >= S * D) return;
    int s = idx / D, c = idx - s * D;
    int j = c >> 1;
    float expo = (c & 1) ? (4.0f * j + 2.0f) / 96.0f : (4.0f * j) / 96.0f;
    float freq = expf(-expo * logf(10000.0f));
    float ang = (float)s * freq;
    pe[idx] = (c & 1) ? cosf(ang) : sinf(ang);
}

// ---------------- embed ----------------
__global__ void embed_kernel(const float* __restrict__ in, const float* __restrict__ pe,
                             float* __restrict__ x) {
    long long idx = (long long)blockIdx.x * 256 + threadIdx.x;
    if (idx >= NTOT) return;
    x[idx] = in[idx] * SQRTD + pe[idx % (S * D)];
}

// ---------------- weight prep ----------------
// wqS: fragment-order [h][n(6)][kk(3)][lane(64)][8] with sqrt(D) folded.
// wkT: [h][e][d] row-major (proj B-frags). pw16: [l][o][c]. w1T: [48][96].
// w2Tp: [96][64] zero-padded.
__global__ void prep_w(const float* __restrict__ WQ, const float* __restrict__ WK,
                       const float* __restrict__ cpw, const float* __restrict__ w1,
                       const float* __restrict__ w2,
                       us* __restrict__ wqS, us* __restrict__ wkT, us* __restrict__ pw16,
                       us* __restrict__ w1T, us* __restrict__ w2Tp) {
    int idx = blockIdx.x * 256 + threadIdx.x;
    if (idx >= H * D * D) return;  // 36864
    int h = idx / (D * D), rem = idx - h * (D * D);
    int d = rem / D, e = rem - d * D;
    // wq fragment order
    int n = e >> 4, lmod = e & 15, kk = d >> 5, ldiv = (d >> 3) & 3, j = d & 7;
    wqS[(size_t)(((h * 6 + n) * 3 + kk) * 64 + ldiv * 16 + lmod) * 8 + j] = f2h(WQ[idx] * SQRTD);
    wkT[(size_t)h * D * D + e * D + d] = f2h(WK[idx]);
    pw16[idx] = f2h(cpw[idx]);  // L*D*D == 36864
    if (idx < 48 * 96) {
        int m = idx / 96, c = idx - m * 96;
        w1T[idx] = f2h(w1[c * 48 + m]);
    }
    if (idx < 96 * 64) {
        int o = idx / 64, m = idx - o * 64;
        w2Tp[idx] = (m < 48) ? f2h(w2[m * 96 + o]) : (us)0;
    }
}

// ---------------- WVO_h = WV_h @ WO_h, stored transposed [h][o][d] (f32 compute) ----------------
__global__ void prep_wvo(const float* __restrict__ WV, const float* __restrict__ WO,
                         us* __restrict__ wvoT) {
    int blk = blockIdx.x;  // 24 = H * 6
    int h = blk / 6, ot = blk - h * 6;
    int tid = threadIdx.x;
    const float* wv = WV + (size_t)h * D * D;  // [d][e]
    const float* wo = WO + (size_t)h * D * D;  // rows e, cols o
    for (int i = tid; i < 16 * 96; i += 256) {
        int o = ot * 16 + i / 96, d = i - (i / 96) * 96;
        float acc = 0.f;
        for (int e = 0; e < 96; e++) acc += wv[d * 96 + e] * wo[e * 96 + o];
        wvoT[(size_t)h * D * D + o * 96 + d] = f2h(acc);
    }
}

// ---------------- layernorm -> f16 ----------------
__global__ void ln16h_kernel(const float* __restrict__ x, const float* __restrict__ gln,
                             const float* __restrict__ bln, us* __restrict__ out) {
    int wave = threadIdx.x >> 6;
    int lane = threadIdx.x & 63;
    int row = blockIdx.x * 4 + wave;
    if (row >= ROWS) return;
    const float* p = x + (size_t)row * D;
    float v0 = p[lane];
    float v1 = (lane < 32) ? p[lane + 64] : 0.f;
    float sm = v0 + v1, q = v0 * v0 + v1 * v1;
    for (int off = 32; off > 0; off >>= 1) {
        sm += __shfl_xor(sm, off);
        q += __shfl_xor(q, off);
    }
    float mean = sm * (1.0f / D);
    float var = q * (1.0f / D) - mean * mean;
    float rstd = rsqrtf(var + 1e-5f);
    us* o = out + (size_t)row * D;
    o[lane] = f2h((v0 - mean) * rstd * gln[lane] + bln[lane]);
    if (lane < 32) o[lane + 64] = f2h((v1 - mean) * rstd * gln[lane + 64] + bln[lane + 64]);
}

// ---------------- fused conv block: LN(+halo) -> dw -> pw MFMA -> xout = xin + relu ----------------
__global__ void conv_fused(const float* __restrict__ xin, float* __restrict__ xout,
                           const float* __restrict__ gln, const float* __restrict__ bln,
                           const float* __restrict__ dwW, const float* __restrict__ dwB,
                           const us* __restrict__ pwW, const float* __restrict__ pwb) {
    __shared__ us lnb[70 * 104];
    __shared__ us dwb[64 * 104];
    __shared__ float lw[96 * 8];
    int tid = threadIdx.x;
    int wave = tid >> 6, lane = tid & 63;
    int r0 = blockIdx.x * 64;
    int b = r0 / S, s0 = r0 % S;

    for (int i = tid; i < 96 * KW; i += 256) lw[(i / KW) * 8 + (i % KW)] = dwW[i];

    for (int i = wave; i < 70; i += 4) {
        int s = s0 - 3 + i;
        bool valid = (unsigned)s < (unsigned)S;
        float v0 = 0.f, v1 = 0.f;
        const float* p = xin + ((size_t)b * S + s) * 96;
        if (valid) {
            v0 = p[lane];
            v1 = (lane < 32) ? p[lane + 64] : 0.f;
        }
        float sm = v0 + v1, q = v0 * v0 + v1 * v1;
        for (int off = 32; off > 0; off >>= 1) {
            sm += __shfl_xor(sm, off);
            q += __shfl_xor(q, off);
        }
        float mean = sm * (1.0f / D);
        float var = q * (1.0f / D) - mean * mean;
        float rstd = rsqrtf(var + 1e-5f);
        lnb[i * 104 + lane] = f2h(valid ? (v0 - mean) * rstd * gln[lane] + bln[lane] : 0.f);
        if (lane < 32)
            lnb[i * 104 + 64 + lane] =
                f2h(valid ? (v1 - mean) * rstd * gln[lane + 64] + bln[lane + 64] : 0.f);
    }
    __syncthreads();

    for (int u = tid; u < 768; u += 256) {
        int j = u / 12, c0 = (u - (u / 12) * 12) * 8;
        float acc[8];
        #pragma unroll
        for (int j2 = 0; j2 < 8; j2++) acc[j2] = dwB[c0 + j2];
        #pragma unroll
        for (int k = 0; k < KW; k++) {
            f16x8 v = ldh(&lnb[(j + k) * 104 + c0]);
            #pragma unroll
            for (int j2 = 0; j2 < 8; j2++) acc[j2] += (float)v[j2] * lw[(c0 + j2) * 8 + k];
        }
        us8 o;
        #pragma unroll
        for (int j2 = 0; j2 < 8; j2++) o[j2] = f2h(acc[j2]);
        *reinterpret_cast<us8*>(&dwb[j * 104 + c0]) = o;
    }
    __syncthreads();

    int lmod = lane & 15, ldiv = lane >> 4, m0 = wave * 16;
    f32x4 acc[6] = {};
    #pragma unroll
    for (int kk = 0; kk < 3; kk++) {
        f16x8 af = ldh(&dwb[(m0 + lmod) * 104 + kk * 32 + ldiv * 8]);
        #pragma unroll
        for (int n = 0; n < 6; n++) {
            f16x8 bf = ldh(pwW + (size_t)(n * 16 + lmod) * 96 + kk * 32 + ldiv * 8);
            acc[n] = __builtin_amdgcn_mfma_f32_16x16x32_f16(af, bf, acc[n], 0, 0, 0);
        }
    }
    #pragma unroll
    for (int n = 0; n < 6; n++) {
        int o = n * 16 + lmod;
        float bv = pwb[o];
        #pragma unroll
        for (int r = 0; r < 4; r++) {
            size_t row = (size_t)r0 + m0 + ldiv * 4 + r;
            xout[row * 96 + o] = xin[row * 96 + o] + fmaxf(acc[n][r] + bv, 0.f);
        }
    }
}

// ---------------- K / V' projection -> fragment-order global layouts ----------------
// grid (ROWS/64, 2H): y -> head = y>>1, type = y&1.
// Kswz: [h][b][tile16(24)][kk(3)][lane][8]; Vswz: [h][b][n(6)][chunk(6)][kk(2)][lane][8].
__global__ void proj_all(const us* __restrict__ h16, const us* __restrict__ wkT,
                         const us* __restrict__ wvoT, us* __restrict__ Kall,
                         us* __restrict__ Vall) {
    __shared__ us stg[96 * 72];  // K: 4 wave-private [16][104]; V: [96 e][72 k]
    int hd = blockIdx.y >> 1, type = blockIdx.y & 1;
    const us* W = (type ? wvoT : wkT) + (size_t)hd * D * D;
    int tid = threadIdx.x;
    int wave = tid >> 6, lane = tid & 63, lmod = lane & 15, ldiv = lane >> 4;
    int row0 = blockIdx.x * 64, m0 = wave * 16;
    int b = row0 / S;

    f32x4 acc[6] = {};
    #pragma unroll
    for (int kk = 0; kk < 3; kk++) {
        f16x8 af = ldh(h16 + (size_t)(row0 + m0 + lmod) * 96 + kk * 32 + ldiv * 8);
        #pragma unroll
        for (int n = 0; n < 6; n++) {
            f16x8 bf = ldh(W + (size_t)(n * 16 + lmod) * 96 + kk * 32 + ldiv * 8);
            acc[n] = __builtin_amdgcn_mfma_f32_16x16x32_f16(af, bf, acc[n], 0, 0, 0);
        }
    }

    if (!type) {
        // wave-private repack: C-layout -> [key row][d] -> fragment order
        us* kT = stg + wave * 1664;  // [16][104]
        #pragma unroll
        for (int n = 0; n < 6; n++)
            #pragma unroll
            for (int r = 0; r < 4; r++)
                kT[(ldiv * 4 + r) * 104 + n * 16 + lmod] = f2h(acc[n][r]);
        int t0 = (row0 % S) / 16 + wave;  // key-tile within b
        us* dst = Kall + (size_t)hd * NTOT + ((size_t)(b * 24 + t0) * 3) * 512;
        #pragma unroll
        for (int kk = 0; kk < 3; kk++) {
            us8 v = *reinterpret_cast<const us8*>(&kT[lmod * 104 + kk * 32 + ldiv * 8]);
            *reinterpret_cast<us8*>(dst + kk * 512 + lane * 8) = v;
        }
    } else {
        // block repack: transpose to [e][k_local], then fragment order per (n, kk)
        #pragma unroll
        for (int n = 0; n < 6; n++)
            #pragma unroll
            for (int r = 0; r < 4; r++)
                stg[(n * 16 + lmod) * 72 + m0 + ldiv * 4 + r] = f2h(acc[n][r]);
        __syncthreads();
        int cblk = (row0 % S) / 64;
        us* dsth = Vall + (size_t)hd * NTOT;
        #pragma unroll
        for (int n = 0; n < 6; n++)
            #pragma unroll
            for (int kk = 0; kk < 2; kk++) {
                us8 v = *reinterpret_cast<const us8*>(&stg[(n * 16 + lmod) * 72 + kk * 32 + ldiv * 8]);
                *reinterpret_cast<us8*>(
                    dsth + ((size_t)((b * 6 + n) * 6 + cblk) * 2 + kk) * 512 + lane * 8) = v;
            }
    }
}

// ---------------- zero-barrier attention: x += sum_h softmax(QK^T) @ V'_h ----------------
// grid 768 (XCD-swizzled), 4 waves; all B-frags coalesced from swizzled global.
__global__ __launch_bounds__(256, 2) void attn_s(const us* __restrict__ h16,
                                                 const us* __restrict__ wqS,
                                                 const us* __restrict__ Kall,
                                                 const us* __restrict__ Vall,
                                                 float* __restrict__ x) {
    __shared__ us qb[4][16 * 104];  // per-wave Q staging
    __shared__ us sP[4][16 * 72];   // per-wave P staging
    int tid = threadIdx.x, wave = tid >> 6, lane = tid & 63;
    int lmod = lane & 15, ldiv = lane >> 4;
    int p = blockIdx.x;
    int gl = (p & 7) * 96 + (p >> 3);  // XCD-chunked swizzle (768 = 8*96)
    int b = gl / 6, q0 = (gl % 6) * 64;
    size_t rowbase = (size_t)b * S + q0 + wave * 16;

    // h A-fragments (head-invariant): 3 loads, once
    f16x8 ah[3];
    #pragma unroll
    for (int kk = 0; kk < 3; kk++)
        ah[kk] = ldh(h16 + (rowbase + lmod) * 96 + kk * 32 + ldiv * 8);

    f32x4 oacc[6] = {};

    for (int hd = 0; hd < H; hd++) {
        const us* Kh = Kall + (size_t)hd * NTOT + (size_t)b * 24 * 1536;
        const us* Vh = Vall + (size_t)hd * NTOT + (size_t)b * 36 * 1024;

        // Q projection (sqrt(D) folded); wq B-frags coalesced
        f32x4 qa[6] = {};
        #pragma unroll
        for (int kk = 0; kk < 3; kk++) {
            #pragma unroll
            for (int n = 0; n < 6; n++) {
                f16x8 bf = ldh(wqS + (size_t)(((hd * 6 + n) * 3 + kk) * 64) * 8 + lane * 8);
                qa[n] = __builtin_amdgcn_mfma_f32_16x16x32_f16(ah[kk], bf, qa[n], 0, 0, 0);
            }
        }
        us* qw = qb[wave];
        #pragma unroll
        for (int n = 0; n < 6; n++)
            #pragma unroll
            for (int r = 0; r < 4; r++)
                qw[(ldiv * 4 + r) * 104 + n * 16 + lmod] = f2h(qa[n][r]);
        f16x8 aq[3];
        #pragma unroll
        for (int kk = 0; kk < 3; kk++) aq[kk] = ldh(&qw[lmod * 104 + kk * 32 + ldiv * 8]);

        // scores = Q @ K^T; K B-frags coalesced (identical across waves -> L1)
        f32x4 sc[24] = {};
        #pragma unroll
        for (int c = 0; c < 6; c++)
            #pragma unroll
            for (int nt = 0; nt < 4; nt++)
                #pragma unroll
                for (int kk = 0; kk < 3; kk++) {
                    f16x8 bf = ldh(Kh + (size_t)((c * 4 + nt) * 3 + kk) * 512 + lane * 8);
                    sc[c * 4 + nt] =
                        __builtin_amdgcn_mfma_f32_16x16x32_f16(aq[kk], bf, sc[c * 4 + nt], 0, 0, 0);
                }

        // in-register softmax
        #pragma unroll
        for (int r = 0; r < 4; r++) {
            float m = -1e30f;
            #pragma unroll
            for (int t = 0; t < 24; t++) m = fmaxf(m, sc[t][r]);
            m = fmaxf(m, __shfl_xor(m, 1));
            m = fmaxf(m, __shfl_xor(m, 2));
            m = fmaxf(m, __shfl_xor(m, 4));
            m = fmaxf(m, __shfl_xor(m, 8));
            float sum = 0.f;
            #pragma unroll
            for (int t = 0; t < 24; t++) {
                float pv = __expf(sc[t][r] - m);
                sc[t][r] = pv;
                sum += pv;
            }
            sum += __shfl_xor(sum, 1);
            sum += __shfl_xor(sum, 2);
            sum += __shfl_xor(sum, 4);
            sum += __shfl_xor(sum, 8);
            float inv = 1.f / sum;
            #pragma unroll
            for (int t = 0; t < 24; t++) sc[t][r] *= inv;
        }

        // oacc += P @ V'; V B-frags coalesced
        #pragma unroll
        for (int c = 0; c < 6; c++) {
            us* pw = sP[wave];
            #pragma unroll
            for (int nt = 0; nt < 4; nt++)
                #pragma unroll
                for (int r = 0; r < 4; r++)
                    pw[(ldiv * 4 + r) * 72 + nt * 16 + lmod] = f2h(sc[c * 4 + nt][r]);
            #pragma unroll
            for (int kk = 0; kk < 2; kk++) {
                f16x8 pf = ldh(&pw[lmod * 72 + kk * 32 + ldiv * 8]);
                #pragma unroll
                for (int n = 0; n < 6; n++) {
                    f16x8 bf = ldh(Vh + (size_t)((n * 6 + c) * 2 + kk) * 512 + lane * 8);
                    oacc[n] = __builtin_amdgcn_mfma_f32_16x16x32_f16(pf, bf, oacc[n], 0, 0, 0);
                }
            }
        }
    }

    // single residual write
    #pragma unroll
    for (int n = 0; n < 6; n++)
        #pragma unroll
        for (int r = 0; r < 4; r++)
            x[(rowbase + ldiv * 4 + r) * 96 + n * 16 + lmod] += oacc[n][r];
}

// ---------------- fused LN + FFN: out = x + sigmoid(LN(x)@w1+b1)@w2+b2 ----------------
__global__ void ffn_ln(const float* __restrict__ x, const float* __restrict__ gln,
                       const float* __restrict__ bln, const us* __restrict__ w1T,
                       const float* __restrict__ b1, const us* __restrict__ w2Tp,
                       const float* __restrict__ b2, float* __restrict__ out) {
    __shared__ us lnb[64 * 104];
    __shared__ us mid[64 * 72];
    int tid = threadIdx.x, wave = tid >> 6, lane = tid & 63;
    int lmod = lane & 15, ldiv = lane >> 4, m0 = wave * 16;
    int row0 = blockIdx.x * 64;

    for (int i = wave; i < 64; i += 4) {
        const float* p = x + (size_t)(row0 + i) * 96;
        float v0 = p[lane];
        float v1 = (lane < 32) ? p[lane + 64] : 0.f;
        float sm = v0 + v1, q = v0 * v0 + v1 * v1;
        for (int off = 32; off > 0; off >>= 1) {
            sm += __shfl_xor(sm, off);
            q += __shfl_xor(q, off);
        }
        float mean = sm * (1.0f / D);
        float var = q * (1.0f / D) - mean * mean;
        float rstd = rsqrtf(var + 1e-5f);
        lnb[i * 104 + lane] = f2h((v0 - mean) * rstd * gln[lane] + bln[lane]);
        if (lane < 32)
            lnb[i * 104 + 64 + lane] = f2h((v1 - mean) * rstd * gln[lane + 64] + bln[lane + 64]);
    }
    __syncthreads();

    f32x4 a3[3] = {};
    #pragma unroll
    for (int kk = 0; kk < 3; kk++) {
        f16x8 af = ldh(&lnb[(m0 + lmod) * 104 + kk * 32 + ldiv * 8]);
        #pragma unroll
        for (int n = 0; n < 3; n++) {
            f16x8 bf = ldh(w1T + (size_t)(n * 16 + lmod) * 96 + kk * 32 + ldiv * 8);
            a3[n] = __builtin_amdgcn_mfma_f32_16x16x32_f16(af, bf, a3[n], 0, 0, 0);
        }
    }
    #pragma unroll
    for (int n = 0; n < 3; n++) {
        float bv = b1[n * 16 + lmod];
        #pragma unroll
        for (int r = 0; r < 4; r++) {
            float v = a3[n][r] + bv;
            mid[(m0 + ldiv * 4 + r) * 72 + n * 16 + lmod] = f2h(1.f / (1.f + __expf(-v)));
        }
    }
    #pragma unroll
    for (int r = 0; r < 4; r++) mid[(m0 + ldiv * 4 + r) * 72 + 48 + lmod] = 0;
    __syncthreads();

    f32x4 a6[6] = {};
    #pragma unroll
    for (int kk = 0; kk < 2; kk++) {
        f16x8 af = ldh(&mid[(m0 + lmod) * 72 + kk * 32 + ldiv * 8]);
        #pragma unroll
        for (int n = 0; n < 6; n++) {
            f16x8 bf = ldh(w2Tp + (size_t)(n * 16 + lmod) * 64 + kk * 32 + ldiv * 8);
            a6[n] = __builtin_amdgcn_mfma_f32_16x16x32_f16(af, bf, a6[n], 0, 0, 0);
        }
    }
    #pragma unroll
    for (int n = 0; n < 6; n++) {
        int o = n * 16 + lmod;
        float bv = b2[o];
        #pragma unroll
        for (int r = 0; r < 4; r++) {
            size_t row = (size_t)row0 + m0 + ldiv * 4 + r;
            out[row * 96 + o] = x[row * 96 + o] + a6[n][r] + bv;
        }
    }
}

extern "C" void kernel_launch(void* const* d_in, const int* in_sizes, int n_in,
                              void* d_out, int out_size, void* d_ws, size_t ws_size,
                              hipStream_t stream) {
    const float* in   = (const float*)d_in[0];
    const float* cdw  = (const float*)d_in[2];
    const float* cdwb = (const float*)d_in[3];
    const float* cpw  = (const float*)d_in[4];
    const float* cpwb = (const float*)d_in[5];
    const float* WQ   = (const float*)d_in[6];
    const float* WK   = (const float*)d_in[7];
    const float* WV   = (const float*)d_in[8];
    const float* WO   = (const float*)d_in[9];
    const float* w1   = (const float*)d_in[10];
    const float* b1   = (const float*)d_in[11];
    const float* w2   = (const float*)d_in[12];
    const float* b2   = (const float*)d_in[13];
    const float* lng  = (const float*)d_in[14];
    const float* lnb  = (const float*)d_in[15];
    float* out = (float*)d_out;
    float* ws = (float*)d_ws;

    float* x   = ws;
    float* pe  = x + NTOT;
    float* x2  = pe + S * D;
    us* h16    = (us*)(x2 + NTOT);
    us* Kall   = h16 + NTOT;               // [H][B][24][3][64][8]
    us* Vall   = Kall + (size_t)H * NTOT;  // [H][B][6][6][2][64][8]
    us* wqS    = Vall + (size_t)H * NTOT;
    us* wkT    = wqS + H * D * D;
    us* wvoT   = wkT + H * D * D;
    us* pw16   = wvoT + H * D * D;
    us* w1T    = pw16 + L * D * D;
    us* w2Tp   = w1T + 48 * 96;
    // total ~= 123 MB

    pe_kernel<<<(S * D + 255) / 256, 256, 0, stream>>>(pe);
    embed_kernel<<<(int)(NTOT / 256), 256, 0, stream>>>(in, pe, x);
    prep_w<<<(H * D * D + 255) / 256, 256, 0, stream>>>(WQ, WK, cpw, w1, w2,
                                                        wqS, wkT, pw16, w1T, w2Tp);
    prep_wvo<<<H * 6, 256, 0, stream>>>(WV, WO, wvoT);

    for (int i = 0; i < L; i++) {
        const float* xi = (i & 1) ? x2 : x;
        float* xo = (i & 1) ? x : x2;
        conv_fused<<<ROWS / 64, 256, 0, stream>>>(xi, xo, lng + i * D, lnb + i * D,
                                                  cdw + i * D * KW, cdwb + i * D,
                                                  pw16 + i * D * D, cpwb + i * D);
    }
    // L=4 even -> result back in x

    ln16h_kernel<<<ROWS / 4, 256, 0, stream>>>(x, lng + L * D, lnb + L * D, h16);
    proj_all<<<dim3(ROWS / 64, 2 * H), 256, 0, stream>>>(h16, wkT, wvoT, Kall, Vall);
    attn_s<<<ROWS / 64, 256, 0, stream>>>(h16, wqS, Kall, Vall, x);

    ffn_ln<<<ROWS / 64, 256, 0, stream>>>(x, lng + (L + 1) * D, lnb + (L + 1) * D,
                                          w1T, b1, w2Tp, b2, out);
}

// Round 9
// 351.169 us; speedup vs baseline: 1.4898x; 1.1498x over previous
//
#include <hip/hip_runtime.h>
#include <math.h>

// EmbeddingEncoder: B=128, S=384, D=96, H=4, K=7, L=4.
// Round 8: flash-style online-softmax attention, 32 q-rows per wave (2 m-tiles,
// 2x B-frag reuse), 6144 single-wave blocks, per-head partials + reduce.
// K/V/Wq remain pre-swizzled in fragment order (coalesced lane*8 loads).

constexpr int B = 128;
constexpr int S = 384;
constexpr int D = 96;
constexpr int H = 4;
constexpr int KW = 7;
constexpr int L = 4;
constexpr int ROWS = B * S;                      // 49152
constexpr long long NTOT = (long long)ROWS * D;  // 4718592
constexpr float SQRTD = 9.797958971132712f;

typedef _Float16 f16x8 __attribute__((ext_vector_type(8)));
typedef float f32x4 __attribute__((ext_vector_type(4)));
typedef unsigned short us;
typedef unsigned short us8 __attribute__((ext_vector_type(8)));

__device__ __forceinline__ us f2h(float f) {
    _Float16 h = (_Float16)f;
    return __builtin_bit_cast(us, h);
}
__device__ __forceinline__ f16x8 ldh(const us* p) {
    return *reinterpret_cast<const f16x8*>(p);
}

// ---------------- positional encoding ----------------
__global__ void pe_kernel(float* __restrict__ pe) {
    int idx = blockIdx.x * 256 + threadIdx.x;
    if (idx >= S * D) return;
    int s = idx / D, c = idx - s * D;
    int j = c >> 1;
    float expo = (c & 1) ? (4.0f * j + 2.0f) / 96.0f : (4.0f * j) / 96.0f;
    float freq = expf(-expo * logf(10000.0f));
    float ang = (float)s * freq;
    pe[idx] = (c & 1) ? cosf(ang) : sinf(ang);
}

// ---------------- embed ----------------
__global__ void embed_kernel(const float* __restrict__ in, const float* __restrict__ pe,
                             float* __restrict__ x) {
    long long idx = (long long)blockIdx.x * 256 + threadIdx.x;
    if (idx >= NTOT) return;
    x[idx] = in[idx] * SQRTD + pe[idx % (S * D)];
}

// ---------------- weight prep ----------------
// wqS: fragment-order [h][n(6)][kk(3)][lane(64)][8] with sqrt(D) folded.
// wkT: [h][e][d] row-major. pw16: [l][o][c]. w1T: [48][96]. w2Tp: [96][64] padded.
__global__ void prep_w(const float* __restrict__ WQ, const float* __restrict__ WK,
                       const float* __restrict__ cpw, const float* __restrict__ w1,
                       const float* __restrict__ w2,
                       us* __restrict__ wqS, us* __restrict__ wkT, us* __restrict__ pw16,
                       us* __restrict__ w1T, us* __restrict__ w2Tp) {
    int idx = blockIdx.x * 256 + threadIdx.x;
    if (idx >= H * D * D) return;  // 36864
    int h = idx / (D * D), rem = idx - h * (D * D);
    int d = rem / D, e = rem - d * D;
    int n = e >> 4, lmod = e & 15, kk = d >> 5, ldiv = (d >> 3) & 3, j = d & 7;
    wqS[(size_t)(((h * 6 + n) * 3 + kk) * 64 + ldiv * 16 + lmod) * 8 + j] = f2h(WQ[idx] * SQRTD);
    wkT[(size_t)h * D * D + e * D + d] = f2h(WK[idx]);
    pw16[idx] = f2h(cpw[idx]);  // L*D*D == 36864
    if (idx < 48 * 96) {
        int m = idx / 96, c = idx - m * 96;
        w1T[idx] = f2h(w1[c * 48 + m]);
    }
    if (idx < 96 * 64) {
        int o = idx / 64, m = idx - o * 64;
        w2Tp[idx] = (m < 48) ? f2h(w2[m * 96 + o]) : (us)0;
    }
}

// ---------------- WVO_h = WV_h @ WO_h, stored transposed [h][o][d] ----------------
__global__ void prep_wvo(const float* __restrict__ WV, const float* __restrict__ WO,
                         us* __restrict__ wvoT) {
    int blk = blockIdx.x;  // 24 = H * 6
    int h = blk / 6, ot = blk - h * 6;
    int tid = threadIdx.x;
    const float* wv = WV + (size_t)h * D * D;
    const float* wo = WO + (size_t)h * D * D;
    for (int i = tid; i < 16 * 96; i += 256) {
        int o = ot * 16 + i / 96, d = i - (i / 96) * 96;
        float acc = 0.f;
        for (int e = 0; e < 96; e++) acc += wv[d * 96 + e] * wo[e * 96 + o];
        wvoT[(size_t)h * D * D + o * 96 + d] = f2h(acc);
    }
}

// ---------------- layernorm -> f16 ----------------
__global__ void ln16h_kernel(const float* __restrict__ x, const float* __restrict__ gln,
                             const float* __restrict__ bln, us* __restrict__ out) {
    int wave = threadIdx.x >> 6;
    int lane = threadIdx.x & 63;
    int row = blockIdx.x * 4 + wave;
    if (row >= ROWS) return;
    const float* p = x + (size_t)row * D;
    float v0 = p[lane];
    float v1 = (lane < 32) ? p[lane + 64] : 0.f;
    float sm = v0 + v1, q = v0 * v0 + v1 * v1;
    for (int off = 32; off > 0; off >>= 1) {
        sm += __shfl_xor(sm, off);
        q += __shfl_xor(q, off);
    }
    float mean = sm * (1.0f / D);
    float var = q * (1.0f / D) - mean * mean;
    float rstd = rsqrtf(var + 1e-5f);
    us* o = out + (size_t)row * D;
    o[lane] = f2h((v0 - mean) * rstd * gln[lane] + bln[lane]);
    if (lane < 32) o[lane + 64] = f2h((v1 - mean) * rstd * gln[lane + 64] + bln[lane + 64]);
}

// ---------------- fused conv block ----------------
__global__ void conv_fused(const float* __restrict__ xin, float* __restrict__ xout,
                           const float* __restrict__ gln, const float* __restrict__ bln,
                           const float* __restrict__ dwW, const float* __restrict__ dwB,
                           const us* __restrict__ pwW, const float* __restrict__ pwb) {
    __shared__ us lnb[70 * 104];
    __shared__ us dwb[64 * 104];
    __shared__ float lw[96 * 8];
    int tid = threadIdx.x;
    int wave = tid >> 6, lane = tid & 63;
    int r0 = blockIdx.x * 64;
    int b = r0 / S, s0 = r0 % S;

    for (int i = tid; i < 96 * KW; i += 256) lw[(i / KW) * 8 + (i % KW)] = dwW[i];

    for (int i = wave; i < 70; i += 4) {
        int s = s0 - 3 + i;
        bool valid = (unsigned)s < (unsigned)S;
        float v0 = 0.f, v1 = 0.f;
        const float* p = xin + ((size_t)b * S + s) * 96;
        if (valid) {
            v0 = p[lane];
            v1 = (lane < 32) ? p[lane + 64] : 0.f;
        }
        float sm = v0 + v1, q = v0 * v0 + v1 * v1;
        for (int off = 32; off > 0; off >>= 1) {
            sm += __shfl_xor(sm, off);
            q += __shfl_xor(q, off);
        }
        float mean = sm * (1.0f / D);
        float var = q * (1.0f / D) - mean * mean;
        float rstd = rsqrtf(var + 1e-5f);
        lnb[i * 104 + lane] = f2h(valid ? (v0 - mean) * rstd * gln[lane] + bln[lane] : 0.f);
        if (lane < 32)
            lnb[i * 104 + 64 + lane] =
                f2h(valid ? (v1 - mean) * rstd * gln[lane + 64] + bln[lane + 64] : 0.f);
    }
    __syncthreads();

    for (int u = tid; u < 768; u += 256) {
        int j = u / 12, c0 = (u - (u / 12) * 12) * 8;
        float acc[8];
        #pragma unroll
        for (int j2 = 0; j2 < 8; j2++) acc[j2] = dwB[c0 + j2];
        #pragma unroll
        for (int k = 0; k < KW; k++) {
            f16x8 v = ldh(&lnb[(j + k) * 104 + c0]);
            #pragma unroll
            for (int j2 = 0; j2 < 8; j2++) acc[j2] += (float)v[j2] * lw[(c0 + j2) * 8 + k];
        }
        us8 o;
        #pragma unroll
        for (int j2 = 0; j2 < 8; j2++) o[j2] = f2h(acc[j2]);
        *reinterpret_cast<us8*>(&dwb[j * 104 + c0]) = o;
    }
    __syncthreads();

    int lmod = lane & 15, ldiv = lane >> 4, m0 = wave * 16;
    f32x4 acc[6] = {};
    #pragma unroll
    for (int kk = 0; kk < 3; kk++) {
        f16x8 af = ldh(&dwb[(m0 + lmod) * 104 + kk * 32 + ldiv * 8]);
        #pragma unroll
        for (int n = 0; n < 6; n++) {
            f16x8 bf = ldh(pwW + (size_t)(n * 16 + lmod) * 96 + kk * 32 + ldiv * 8);
            acc[n] = __builtin_amdgcn_mfma_f32_16x16x32_f16(af, bf, acc[n], 0, 0, 0);
        }
    }
    #pragma unroll
    for (int n = 0; n < 6; n++) {
        int o = n * 16 + lmod;
        float bv = pwb[o];
        #pragma unroll
        for (int r = 0; r < 4; r++) {
            size_t row = (size_t)r0 + m0 + ldiv * 4 + r;
            xout[row * 96 + o] = xin[row * 96 + o] + fmaxf(acc[n][r] + bv, 0.f);
        }
    }
}

// ---------------- K / V' projection -> fragment-order global layouts ----------------
__global__ void proj_all(const us* __restrict__ h16, const us* __restrict__ wkT,
                         const us* __restrict__ wvoT, us* __restrict__ Kall,
                         us* __restrict__ Vall) {
    __shared__ us stg[96 * 72];
    int hd = blockIdx.y >> 1, type = blockIdx.y & 1;
    const us* W = (type ? wvoT : wkT) + (size_t)hd * D * D;
    int tid = threadIdx.x;
    int wave = tid >> 6, lane = tid & 63, lmod = lane & 15, ldiv = lane >> 4;
    int row0 = blockIdx.x * 64, m0 = wave * 16;
    int b = row0 / S;

    f32x4 acc[6] = {};
    #pragma unroll
    for (int kk = 0; kk < 3; kk++) {
        f16x8 af = ldh(h16 + (size_t)(row0 + m0 + lmod) * 96 + kk * 32 + ldiv * 8);
        #pragma unroll
        for (int n = 0; n < 6; n++) {
            f16x8 bf = ldh(W + (size_t)(n * 16 + lmod) * 96 + kk * 32 + ldiv * 8);
            acc[n] = __builtin_amdgcn_mfma_f32_16x16x32_f16(af, bf, acc[n], 0, 0, 0);
        }
    }

    if (!type) {
        us* kT = stg + wave * 1664;  // [16][104]
        #pragma unroll
        for (int n = 0; n < 6; n++)
            #pragma unroll
            for (int r = 0; r < 4; r++)
                kT[(ldiv * 4 + r) * 104 + n * 16 + lmod] = f2h(acc[n][r]);
        int t0 = (row0 % S) / 16 + wave;
        us* dst = Kall + (size_t)hd * NTOT + ((size_t)(b * 24 + t0) * 3) * 512;
        #pragma unroll
        for (int kk = 0; kk < 3; kk++) {
            us8 v = *reinterpret_cast<const us8*>(&kT[lmod * 104 + kk * 32 + ldiv * 8]);
            *reinterpret_cast<us8*>(dst + kk * 512 + lane * 8) = v;
        }
    } else {
        #pragma unroll
        for (int n = 0; n < 6; n++)
            #pragma unroll
            for (int r = 0; r < 4; r++)
                stg[(n * 16 + lmod) * 72 + m0 + ldiv * 4 + r] = f2h(acc[n][r]);
        __syncthreads();
        int cblk = (row0 % S) / 64;
        us* dsth = Vall + (size_t)hd * NTOT;
        #pragma unroll
        for (int n = 0; n < 6; n++)
            #pragma unroll
            for (int kk = 0; kk < 2; kk++) {
                us8 v = *reinterpret_cast<const us8*>(&stg[(n * 16 + lmod) * 72 + kk * 32 + ldiv * 8]);
                *reinterpret_cast<us8*>(
                    dsth + ((size_t)((b * 6 + n) * 6 + cblk) * 2 + kk) * 512 + lane * 8) = v;
            }
    }
}

// ---------------- flash attention: one wave, 32 q-rows, one head -> xpart[hd] ----------------
// grid 6144 = B * 12 * H (XCD-swizzled), 64 threads.
__global__ __launch_bounds__(64, 3) void attn_h32(const us* __restrict__ h16,
                                                  const us* __restrict__ wqS,
                                                  const us* __restrict__ Kall,
                                                  const us* __restrict__ Vall,
                                                  us* __restrict__ xpart) {
    __shared__ us qb[32 * 104];
    __shared__ us sP[32 * 72];
    int lane = threadIdx.x;
    int lmod = lane & 15, ldiv = lane >> 4;
    int p = blockIdx.x;
    int gl = (p & 7) * 768 + (p >> 3);  // 6144 = 8 * 768, XCD-chunked
    int t = gl % 12;                    // 32-row q-tile
    int bh = gl / 12;                   // b*H + hd
    int b = bh >> 2, hd = bh & 3;
    size_t rowbase = (size_t)b * S + t * 32;

    // h A-frags for both m-tiles
    f16x8 ah0[3], ah1[3];
    #pragma unroll
    for (int kk = 0; kk < 3; kk++) {
        ah0[kk] = ldh(h16 + (rowbase + lmod) * 96 + kk * 32 + ldiv * 8);
        ah1[kk] = ldh(h16 + (rowbase + 16 + lmod) * 96 + kk * 32 + ldiv * 8);
    }

    // Q projection (sqrt(D) folded); wq B-frags reused across both m-tiles
    f32x4 qa0[6] = {}, qa1[6] = {};
    #pragma unroll
    for (int kk = 0; kk < 3; kk++)
        #pragma unroll
        for (int n = 0; n < 6; n++) {
            f16x8 bf = ldh(wqS + (size_t)(((hd * 6 + n) * 3 + kk) * 64) * 8 + lane * 8);
            qa0[n] = __builtin_amdgcn_mfma_f32_16x16x32_f16(ah0[kk], bf, qa0[n], 0, 0, 0);
            qa1[n] = __builtin_amdgcn_mfma_f32_16x16x32_f16(ah1[kk], bf, qa1[n], 0, 0, 0);
        }
    #pragma unroll
    for (int n = 0; n < 6; n++)
        #pragma unroll
        for (int r = 0; r < 4; r++) {
            qb[(ldiv * 4 + r) * 104 + n * 16 + lmod] = f2h(qa0[n][r]);
            qb[(16 + ldiv * 4 + r) * 104 + n * 16 + lmod] = f2h(qa1[n][r]);
        }
    f16x8 aq0[3], aq1[3];
    #pragma unroll
    for (int kk = 0; kk < 3; kk++) {
        aq0[kk] = ldh(&qb[lmod * 104 + kk * 32 + ldiv * 8]);
        aq1[kk] = ldh(&qb[(16 + lmod) * 104 + kk * 32 + ldiv * 8]);
    }

    const us* Kh = Kall + (size_t)hd * NTOT + (size_t)b * 24 * 1536;
    const us* Vh = Vall + (size_t)hd * NTOT + (size_t)b * 36 * 1024;

    f32x4 oacc0[6] = {}, oacc1[6] = {};
    f32x4 m0v = {-1e30f, -1e30f, -1e30f, -1e30f}, m1v = m0v;
    f32x4 l0v = {}, l1v = {};

    for (int c = 0; c < 6; c++) {
        // chunk scores (64 keys)
        f32x4 s0[4] = {}, s1[4] = {};
        #pragma unroll
        for (int nt = 0; nt < 4; nt++)
            #pragma unroll
            for (int kk = 0; kk < 3; kk++) {
                f16x8 bf = ldh(Kh + (size_t)((c * 4 + nt) * 3 + kk) * 512 + lane * 8);
                s0[nt] = __builtin_amdgcn_mfma_f32_16x16x32_f16(aq0[kk], bf, s0[nt], 0, 0, 0);
                s1[nt] = __builtin_amdgcn_mfma_f32_16x16x32_f16(aq1[kk], bf, s1[nt], 0, 0, 0);
            }

        // online softmax update, m-tile 0
        #pragma unroll
        for (int r = 0; r < 4; r++) {
            float cm = fmaxf(fmaxf(s0[0][r], s0[1][r]), fmaxf(s0[2][r], s0[3][r]));
            cm = fmaxf(cm, __shfl_xor(cm, 1));
            cm = fmaxf(cm, __shfl_xor(cm, 2));
            cm = fmaxf(cm, __shfl_xor(cm, 4));
            cm = fmaxf(cm, __shfl_xor(cm, 8));
            float mn = fmaxf(m0v[r], cm);
            float scl = __expf(m0v[r] - mn);
            m0v[r] = mn;
            float ssum = 0.f;
            #pragma unroll
            for (int nt = 0; nt < 4; nt++) {
                float pv = __expf(s0[nt][r] - mn);
                s0[nt][r] = pv;
                ssum += pv;
            }
            ssum += __shfl_xor(ssum, 1);
            ssum += __shfl_xor(ssum, 2);
            ssum += __shfl_xor(ssum, 4);
            ssum += __shfl_xor(ssum, 8);
            l0v[r] = l0v[r] * scl + ssum;
            #pragma unroll
            for (int n = 0; n < 6; n++) oacc0[n][r] *= scl;
            #pragma unroll
            for (int nt = 0; nt < 4; nt++)
                sP[(ldiv * 4 + r) * 72 + nt * 16 + lmod] = f2h(s0[nt][r]);
        }
        // m-tile 1
        #pragma unroll
        for (int r = 0; r < 4; r++) {
            float cm = fmaxf(fmaxf(s1[0][r], s1[1][r]), fmaxf(s1[2][r], s1[3][r]));
            cm = fmaxf(cm, __shfl_xor(cm, 1));
            cm = fmaxf(cm, __shfl_xor(cm, 2));
            cm = fmaxf(cm, __shfl_xor(cm, 4));
            cm = fmaxf(cm, __shfl_xor(cm, 8));
            float mn = fmaxf(m1v[r], cm);
            float scl = __expf(m1v[r] - mn);
            m1v[r] = mn;
            float ssum = 0.f;
            #pragma unroll
            for (int nt = 0; nt < 4; nt++) {
                float pv = __expf(s1[nt][r] - mn);
                s1[nt][r] = pv;
                ssum += pv;
            }
            ssum += __shfl_xor(ssum, 1);
            ssum += __shfl_xor(ssum, 2);
            ssum += __shfl_xor(ssum, 4);
            ssum += __shfl_xor(ssum, 8);
            l1v[r] = l1v[r] * scl + ssum;
            #pragma unroll
            for (int n = 0; n < 6; n++) oacc1[n][r] *= scl;
            #pragma unroll
            for (int nt = 0; nt < 4; nt++)
                sP[(16 + ldiv * 4 + r) * 72 + nt * 16 + lmod] = f2h(s1[nt][r]);
        }

        // PV for this chunk; V B-frags reused across both m-tiles
        #pragma unroll
        for (int kk = 0; kk < 2; kk++) {
            f16x8 pf0 = ldh(&sP[lmod * 72 + kk * 32 + ldiv * 8]);
            f16x8 pf1 = ldh(&sP[(16 + lmod) * 72 + kk * 32 + ldiv * 8]);
            #pragma unroll
            for (int n = 0; n < 6; n++) {
                f16x8 bf = ldh(Vh + (size_t)((n * 6 + c) * 2 + kk) * 512 + lane * 8);
                oacc0[n] = __builtin_amdgcn_mfma_f32_16x16x32_f16(pf0, bf, oacc0[n], 0, 0, 0);
                oacc1[n] = __builtin_amdgcn_mfma_f32_16x16x32_f16(pf1, bf, oacc1[n], 0, 0, 0);
            }
        }
    }

    // finalize: divide by l, write per-head partial (f16)
    us* xp = xpart + (size_t)hd * NTOT;
    #pragma unroll
    for (int r = 0; r < 4; r++) {
        float inv0 = 1.f / l0v[r];
        float inv1 = 1.f / l1v[r];
        #pragma unroll
        for (int n = 0; n < 6; n++) {
            xp[(rowbase + ldiv * 4 + r) * 96 + n * 16 + lmod] = f2h(oacc0[n][r] * inv0);
            xp[(rowbase + 16 + ldiv * 4 + r) * 96 + n * 16 + lmod] = f2h(oacc1[n][r] * inv1);
        }
    }
}

// ---------------- x += sum_h xpart[h] ----------------
__global__ void reduce4(const us* __restrict__ xpart, float* __restrict__ x) {
    long long idx = ((long long)blockIdx.x * 256 + threadIdx.x) * 8;
    if (idx >= NTOT) return;
    float4* xp = reinterpret_cast<float4*>(x + idx);
    float4 a0 = xp[0], a1 = xp[1];
    float acc[8] = {a0.x, a0.y, a0.z, a0.w, a1.x, a1.y, a1.z, a1.w};
    #pragma unroll
    for (int h = 0; h < H; h++) {
        f16x8 v = ldh(xpart + (size_t)h * NTOT + idx);
        #pragma unroll
        for (int j = 0; j < 8; j++) acc[j] += (float)v[j];
    }
    xp[0] = float4{acc[0], acc[1], acc[2], acc[3]};
    xp[1] = float4{acc[4], acc[5], acc[6], acc[7]};
}

// ---------------- fused LN + FFN ----------------
__global__ void ffn_ln(const float* __restrict__ x, const float* __restrict__ gln,
                       const float* __restrict__ bln, const us* __restrict__ w1T,
                       const float* __restrict__ b1, const us* __restrict__ w2Tp,
                       const float* __restrict__ b2, float* __restrict__ out) {
    __shared__ us lnb[64 * 104];
    __shared__ us mid[64 * 72];
    int tid = threadIdx.x, wave = tid >> 6, lane = tid & 63;
    int lmod = lane & 15, ldiv = lane >> 4, m0 = wave * 16;
    int row0 = blockIdx.x * 64;

    for (int i = wave; i < 64; i += 4) {
        const float* p = x + (size_t)(row0 + i) * 96;
        float v0 = p[lane];
        float v1 = (lane < 32) ? p[lane + 64] : 0.f;
        float sm = v0 + v1, q = v0 * v0 + v1 * v1;
        for (int off = 32; off > 0; off >>= 1) {
            sm += __shfl_xor(sm, off);
            q += __shfl_xor(q, off);
        }
        float mean = sm * (1.0f / D);
        float var = q * (1.0f / D) - mean * mean;
        float rstd = rsqrtf(var + 1e-5f);
        lnb[i * 104 + lane] = f2h((v0 - mean) * rstd * gln[lane] + bln[lane]);
        if (lane < 32)
            lnb[i * 104 + 64 + lane] = f2h((v1 - mean) * rstd * gln[lane + 64] + bln[lane + 64]);
    }
    __syncthreads();

    f32x4 a3[3] = {};
    #pragma unroll
    for (int kk = 0; kk < 3; kk++) {
        f16x8 af = ldh(&lnb[(m0 + lmod) * 104 + kk * 32 + ldiv * 8]);
        #pragma unroll
        for (int n = 0; n < 3; n++) {
            f16x8 bf = ldh(w1T + (size_t)(n * 16 + lmod) * 96 + kk * 32 + ldiv * 8);
            a3[n] = __builtin_amdgcn_mfma_f32_16x16x32_f16(af, bf, a3[n], 0, 0, 0);
        }
    }
    #pragma unroll
    for (int n = 0; n < 3; n++) {
        float bv = b1[n * 16 + lmod];
        #pragma unroll
        for (int r = 0; r < 4; r++) {
            float v = a3[n][r] + bv;
            mid[(m0 + ldiv * 4 + r) * 72 + n * 16 + lmod] = f2h(1.f / (1.f + __expf(-v)));
        }
    }
    #pragma unroll
    for (int r = 0; r < 4; r++) mid[(m0 + ldiv * 4 + r) * 72 + 48 + lmod] = 0;
    __syncthreads();

    f32x4 a6[6] = {};
    #pragma unroll
    for (int kk = 0; kk < 2; kk++) {
        f16x8 af = ldh(&mid[(m0 + lmod) * 72 + kk * 32 + ldiv * 8]);
        #pragma unroll
        for (int n = 0; n < 6; n++) {
            f16x8 bf = ldh(w2Tp + (size_t)(n * 16 + lmod) * 64 + kk * 32 + ldiv * 8);
            a6[n] = __builtin_amdgcn_mfma_f32_16x16x32_f16(af, bf, a6[n], 0, 0, 0);
        }
    }
    #pragma unroll
    for (int n = 0; n < 6; n++) {
        int o = n * 16 + lmod;
        float bv = b2[o];
        #pragma unroll
        for (int r = 0; r < 4; r++) {
            size_t row = (size_t)row0 + m0 + ldiv * 4 + r;
            out[row * 96 + o] = x[row * 96 + o] + a6[n][r] + bv;
        }
    }
}

extern "C" void kernel_launch(void* const* d_in, const int* in_sizes, int n_in,
                              void* d_out, int out_size, void* d_ws, size_t ws_size,
                              hipStream_t stream) {
    const float* in   = (const float*)d_in[0];
    const float* cdw  = (const float*)d_in[2];
    const float* cdwb = (const float*)d_in[3];
    const float* cpw  = (const float*)d_in[4];
    const float* cpwb = (const float*)d_in[5];
    const float* WQ   = (const float*)d_in[6];
    const float* WK   = (const float*)d_in[7];
    const float* WV   = (const float*)d_in[8];
    const float* WO   = (const float*)d_in[9];
    const float* w1   = (const float*)d_in[10];
    const float* b1   = (const float*)d_in[11];
    const float* w2   = (const float*)d_in[12];
    const float* b2   = (const float*)d_in[13];
    const float* lng  = (const float*)d_in[14];
    const float* lnb  = (const float*)d_in[15];
    float* out = (float*)d_out;
    float* ws = (float*)d_ws;

    float* x   = ws;
    float* pe  = x + NTOT;
    float* x2  = pe + S * D;
    us* h16    = (us*)(x2 + NTOT);
    us* Kall   = h16 + NTOT;               // [H][B][24][3][64][8]
    us* Vall   = Kall + (size_t)H * NTOT;  // [H][B][6][6][2][64][8]
    us* xpart  = Vall + (size_t)H * NTOT;  // [H][ROWS][96]
    us* wqS    = xpart + (size_t)H * NTOT;
    us* wkT    = wqS + H * D * D;
    us* wvoT   = wkT + H * D * D;
    us* pw16   = wvoT + H * D * D;
    us* w1T    = pw16 + L * D * D;
    us* w2Tp   = w1T + 48 * 96;
    // total ~= 161 MB (< 256 MB ws)

    pe_kernel<<<(S * D + 255) / 256, 256, 0, stream>>>(pe);
    embed_kernel<<<(int)(NTOT / 256), 256, 0, stream>>>(in, pe, x);
    prep_w<<<(H * D * D + 255) / 256, 256, 0, stream>>>(WQ, WK, cpw, w1, w2,
                                                        wqS, wkT, pw16, w1T, w2Tp);
    prep_wvo<<<H * 6, 256, 0, stream>>>(WV, WO, wvoT);

    for (int i = 0; i < L; i++) {
        const float* xi = (i & 1) ? x2 : x;
        float* xo = (i & 1) ? x : x2;
        conv_fused<<<ROWS / 64, 256, 0, stream>>>(xi, xo, lng + i * D, lnb + i * D,
                                                  cdw + i * D * KW, cdwb + i * D,
                                                  pw16 + i * D * D, cpwb + i * D);
    }
    // L=4 even -> result back in x

    ln16h_kernel<<<ROWS / 4, 256, 0, stream>>>(x, lng + L * D, lnb + L * D, h16);
    proj_all<<<dim3(ROWS / 64, 2 * H), 256, 0, stream>>>(h16, wkT, wvoT, Kall, Vall);
    attn_h32<<<B * 12 * H, 64, 0, stream>>>(h16, wqS, Kall, Vall, xpart);
    reduce4<<<(int)(NTOT / 8 / 256), 256, 0, stream>>>(xpart, x);

    ffn_ln<<<ROWS / 64, 256, 0, stream>>>(x, lng + (L + 1) * D, lnb + (L + 1) * D,
                                          w1T, b1, w2Tp, b2, out);
}

// Round 10
// 346.024 us; speedup vs baseline: 1.5119x; 1.0149x over previous
//
#include <hip/hip_runtime.h>
#include <math.h>

// EmbeddingEncoder: B=128, S=384, D=96, H=4, K=7, L=4.
// Round 9: attn LDS merge (Q/P staging share one buffer -> 2x occupancy cap),
// reduce4 fused into ffn_ln, embed fused into conv layer 0, proj K/V merged.

constexpr int B = 128;
constexpr int S = 384;
constexpr int D = 96;
constexpr int H = 4;
constexpr int KW = 7;
constexpr int L = 4;
constexpr int ROWS = B * S;                      // 49152
constexpr long long NTOT = (long long)ROWS * D;  // 4718592
constexpr float SQRTD = 9.797958971132712f;

typedef _Float16 f16x8 __attribute__((ext_vector_type(8)));
typedef float f32x4 __attribute__((ext_vector_type(4)));
typedef unsigned short us;
typedef unsigned short us8 __attribute__((ext_vector_type(8)));

__device__ __forceinline__ us f2h(float f) {
    _Float16 h = (_Float16)f;
    return __builtin_bit_cast(us, h);
}
__device__ __forceinline__ f16x8 ldh(const us* p) {
    return *reinterpret_cast<const f16x8*>(p);
}

// ---------------- positional encoding ----------------
__global__ void pe_kernel(float* __restrict__ pe) {
    int idx = blockIdx.x * 256 + threadIdx.x;
    if (idx >= S * D) return;
    int s = idx / D, c = idx - s * D;
    int j = c >> 1;
    float expo = (c & 1) ? (4.0f * j + 2.0f) / 96.0f : (4.0f * j) / 96.0f;
    float freq = expf(-expo * logf(10000.0f));
    float ang = (float)s * freq;
    pe[idx] = (c & 1) ? cosf(ang) : sinf(ang);
}

// ---------------- weight prep ----------------
// wqS: fragment-order [h][n(6)][kk(3)][lane(64)][8] with sqrt(D) folded.
// wkT: [h][e][d] row-major. pw16: [l][o][c]. w1T: [48][96]. w2Tp: [96][64] padded.
__global__ void prep_w(const float* __restrict__ WQ, const float* __restrict__ WK,
                       const float* __restrict__ cpw, const float* __restrict__ w1,
                       const float* __restrict__ w2,
                       us* __restrict__ wqS, us* __restrict__ wkT, us* __restrict__ pw16,
                       us* __restrict__ w1T, us* __restrict__ w2Tp) {
    int idx = blockIdx.x * 256 + threadIdx.x;
    if (idx >= H * D * D) return;  // 36864
    int h = idx / (D * D), rem = idx - h * (D * D);
    int d = rem / D, e = rem - d * D;
    int n = e >> 4, lmod = e & 15, kk = d >> 5, ldiv = (d >> 3) & 3, j = d & 7;
    wqS[(size_t)(((h * 6 + n) * 3 + kk) * 64 + ldiv * 16 + lmod) * 8 + j] = f2h(WQ[idx] * SQRTD);
    wkT[(size_t)h * D * D + e * D + d] = f2h(WK[idx]);
    pw16[idx] = f2h(cpw[idx]);  // L*D*D == 36864
    if (idx < 48 * 96) {
        int m = idx / 96, c = idx - m * 96;
        w1T[idx] = f2h(w1[c * 48 + m]);
    }
    if (idx < 96 * 64) {
        int o = idx / 64, m = idx - o * 64;
        w2Tp[idx] = (m < 48) ? f2h(w2[m * 96 + o]) : (us)0;
    }
}

// ---------------- WVO_h = WV_h @ WO_h, stored transposed [h][o][d] ----------------
__global__ void prep_wvo(const float* __restrict__ WV, const float* __restrict__ WO,
                         us* __restrict__ wvoT) {
    int blk = blockIdx.x;  // 24 = H * 6
    int h = blk / 6, ot = blk - h * 6;
    int tid = threadIdx.x;
    const float* wv = WV + (size_t)h * D * D;
    const float* wo = WO + (size_t)h * D * D;
    for (int i = tid; i < 16 * 96; i += 256) {
        int o = ot * 16 + i / 96, d = i - (i / 96) * 96;
        float acc = 0.f;
        for (int e = 0; e < 96; e++) acc += wv[d * 96 + e] * wo[e * 96 + o];
        wvoT[(size_t)h * D * D + o * 96 + d] = f2h(acc);
    }
}

// ---------------- layernorm -> f16 ----------------
__global__ void ln16h_kernel(const float* __restrict__ x, const float* __restrict__ gln,
                             const float* __restrict__ bln, us* __restrict__ out) {
    int wave = threadIdx.x >> 6;
    int lane = threadIdx.x & 63;
    int row = blockIdx.x * 4 + wave;
    if (row >= ROWS) return;
    const float* p = x + (size_t)row * D;
    float v0 = p[lane];
    float v1 = (lane < 32) ? p[lane + 64] : 0.f;
    float sm = v0 + v1, q = v0 * v0 + v1 * v1;
    for (int off = 32; off > 0; off >>= 1) {
        sm += __shfl_xor(sm, off);
        q += __shfl_xor(q, off);
    }
    float mean = sm * (1.0f / D);
    float var = q * (1.0f / D) - mean * mean;
    float rstd = rsqrtf(var + 1e-5f);
    us* o = out + (size_t)row * D;
    o[lane] = f2h((v0 - mean) * rstd * gln[lane] + bln[lane]);
    if (lane < 32) o[lane + 64] = f2h((v1 - mean) * rstd * gln[lane + 64] + bln[lane + 64]);
}

// ---------------- fused conv block (EMBED=1: layer 0 computes in*sqrtD+pe inline) ----------------
template <int EMBED>
__global__ void conv_fused_t(const float* __restrict__ xin, const float* __restrict__ inp,
                             const float* __restrict__ pe, float* __restrict__ xout,
                             const float* __restrict__ gln, const float* __restrict__ bln,
                             const float* __restrict__ dwW, const float* __restrict__ dwB,
                             const us* __restrict__ pwW, const float* __restrict__ pwb) {
    __shared__ us lnb[70 * 104];
    __shared__ us dwb[64 * 104];
    __shared__ float lw[96 * 8];
    int tid = threadIdx.x;
    int wave = tid >> 6, lane = tid & 63;
    int r0 = blockIdx.x * 64;
    int b = r0 / S, s0 = r0 % S;

    for (int i = tid; i < 96 * KW; i += 256) lw[(i / KW) * 8 + (i % KW)] = dwW[i];

    for (int i = wave; i < 70; i += 4) {
        int s = s0 - 3 + i;
        bool valid = (unsigned)s < (unsigned)S;
        float v0 = 0.f, v1 = 0.f;
        if (valid) {
            size_t ro = ((size_t)b * S + s) * 96;
            if (EMBED) {
                v0 = inp[ro + lane] * SQRTD + pe[s * 96 + lane];
                v1 = (lane < 32) ? inp[ro + 64 + lane] * SQRTD + pe[s * 96 + 64 + lane] : 0.f;
            } else {
                v0 = xin[ro + lane];
                v1 = (lane < 32) ? xin[ro + 64 + lane] : 0.f;
            }
        }
        float sm = v0 + v1, q = v0 * v0 + v1 * v1;
        for (int off = 32; off > 0; off >>= 1) {
            sm += __shfl_xor(sm, off);
            q += __shfl_xor(q, off);
        }
        float mean = sm * (1.0f / D);
        float var = q * (1.0f / D) - mean * mean;
        float rstd = rsqrtf(var + 1e-5f);
        lnb[i * 104 + lane] = f2h(valid ? (v0 - mean) * rstd * gln[lane] + bln[lane] : 0.f);
        if (lane < 32)
            lnb[i * 104 + 64 + lane] =
                f2h(valid ? (v1 - mean) * rstd * gln[lane + 64] + bln[lane + 64] : 0.f);
    }
    __syncthreads();

    for (int u = tid; u < 768; u += 256) {
        int j = u / 12, c0 = (u - (u / 12) * 12) * 8;
        float acc[8];
        #pragma unroll
        for (int j2 = 0; j2 < 8; j2++) acc[j2] = dwB[c0 + j2];
        #pragma unroll
        for (int k = 0; k < KW; k++) {
            f16x8 v = ldh(&lnb[(j + k) * 104 + c0]);
            #pragma unroll
            for (int j2 = 0; j2 < 8; j2++) acc[j2] += (float)v[j2] * lw[(c0 + j2) * 8 + k];
        }
        us8 o;
        #pragma unroll
        for (int j2 = 0; j2 < 8; j2++) o[j2] = f2h(acc[j2]);
        *reinterpret_cast<us8*>(&dwb[j * 104 + c0]) = o;
    }
    __syncthreads();

    int lmod = lane & 15, ldiv = lane >> 4, m0 = wave * 16;
    f32x4 acc[6] = {};
    #pragma unroll
    for (int kk = 0; kk < 3; kk++) {
        f16x8 af = ldh(&dwb[(m0 + lmod) * 104 + kk * 32 + ldiv * 8]);
        #pragma unroll
        for (int n = 0; n < 6; n++) {
            f16x8 bf = ldh(pwW + (size_t)(n * 16 + lmod) * 96 + kk * 32 + ldiv * 8);
            acc[n] = __builtin_amdgcn_mfma_f32_16x16x32_f16(af, bf, acc[n], 0, 0, 0);
        }
    }
    #pragma unroll
    for (int n = 0; n < 6; n++) {
        int o = n * 16 + lmod;
        float bv = pwb[o];
        #pragma unroll
        for (int r = 0; r < 4; r++) {
            int sr = m0 + ldiv * 4 + r;
            size_t row = (size_t)r0 + sr;
            float base;
            if (EMBED)
                base = inp[row * 96 + o] * SQRTD + pe[(s0 + sr) * 96 + o];
            else
                base = xin[row * 96 + o];
            xout[row * 96 + o] = base + fmaxf(acc[n][r] + bv, 0.f);
        }
    }
}

// ---------------- K + V' projection (both types per block) -> fragment-order layouts ----------------
// grid (ROWS/64, H).
__global__ void proj_all(const us* __restrict__ h16, const us* __restrict__ wkT,
                         const us* __restrict__ wvoT, us* __restrict__ Kall,
                         us* __restrict__ Vall) {
    __shared__ us stg[96 * 72];
    int hd = blockIdx.y;
    int tid = threadIdx.x;
    int wave = tid >> 6, lane = tid & 63, lmod = lane & 15, ldiv = lane >> 4;
    int row0 = blockIdx.x * 64, m0 = wave * 16;
    int b = row0 / S;

    // h A-frags once, reused for K and V'
    f16x8 af[3];
    #pragma unroll
    for (int kk = 0; kk < 3; kk++)
        af[kk] = ldh(h16 + (size_t)(row0 + m0 + lmod) * 96 + kk * 32 + ldiv * 8);

    // ---- K ----
    {
        const us* W = wkT + (size_t)hd * D * D;
        f32x4 acc[6] = {};
        #pragma unroll
        for (int kk = 0; kk < 3; kk++)
            #pragma unroll
            for (int n = 0; n < 6; n++) {
                f16x8 bf = ldh(W + (size_t)(n * 16 + lmod) * 96 + kk * 32 + ldiv * 8);
                acc[n] = __builtin_amdgcn_mfma_f32_16x16x32_f16(af[kk], bf, acc[n], 0, 0, 0);
            }
        us* kT = stg + wave * 1664;  // wave-private [16][104]
        #pragma unroll
        for (int n = 0; n < 6; n++)
            #pragma unroll
            for (int r = 0; r < 4; r++)
                kT[(ldiv * 4 + r) * 104 + n * 16 + lmod] = f2h(acc[n][r]);
        int t0 = (row0 % S) / 16 + wave;
        us* dst = Kall + (size_t)hd * NTOT + ((size_t)(b * 24 + t0) * 3) * 512;
        #pragma unroll
        for (int kk = 0; kk < 3; kk++) {
            us8 v = *reinterpret_cast<const us8*>(&kT[lmod * 104 + kk * 32 + ldiv * 8]);
            *reinterpret_cast<us8*>(dst + kk * 512 + lane * 8) = v;
        }
    }
    __syncthreads();

    // ---- V' ----
    {
        const us* W = wvoT + (size_t)hd * D * D;
        f32x4 acc[6] = {};
        #pragma unroll
        for (int kk = 0; kk < 3; kk++)
            #pragma unroll
            for (int n = 0; n < 6; n++) {
                f16x8 bf = ldh(W + (size_t)(n * 16 + lmod) * 96 + kk * 32 + ldiv * 8);
                acc[n] = __builtin_amdgcn_mfma_f32_16x16x32_f16(af[kk], bf, acc[n], 0, 0, 0);
            }
        #pragma unroll
        for (int n = 0; n < 6; n++)
            #pragma unroll
            for (int r = 0; r < 4; r++)
                stg[(n * 16 + lmod) * 72 + m0 + ldiv * 4 + r] = f2h(acc[n][r]);
        __syncthreads();
        int cblk = (row0 % S) / 64;
        us* dsth = Vall + (size_t)hd * NTOT;
        #pragma unroll
        for (int n = 0; n < 6; n++)
            #pragma unroll
            for (int kk = 0; kk < 2; kk++) {
                us8 v =
                    *reinterpret_cast<const us8*>(&stg[(n * 16 + lmod) * 72 + kk * 32 + ldiv * 8]);
                *reinterpret_cast<us8*>(
                    dsth + ((size_t)((b * 6 + n) * 6 + cblk) * 2 + kk) * 512 + lane * 8) = v;
            }
    }
}

// ---------------- flash attention: one wave, 32 q-rows, one head -> xpart[hd] ----------------
// grid 6144 = B * 12 * H (XCD-swizzled), 64 threads. Single merged LDS buffer (6656 B).
__global__ __launch_bounds__(64, 3) void attn_h32(const us* __restrict__ h16,
                                                  const us* __restrict__ wqS,
                                                  const us* __restrict__ Kall,
                                                  const us* __restrict__ Vall,
                                                  us* __restrict__ xpart) {
    __shared__ us stg[32 * 104];  // Q staging, then P staging (in-order LDS, wave-private)
    int lane = threadIdx.x;
    int lmod = lane & 15, ldiv = lane >> 4;
    int p = blockIdx.x;
    int gl = (p & 7) * 768 + (p >> 3);  // 6144 = 8 * 768, XCD-chunked
    int t = gl % 12;
    int bh = gl / 12;
    int b = bh >> 2, hd = bh & 3;
    size_t rowbase = (size_t)b * S + t * 32;

    // h A-frags for both m-tiles
    f16x8 ah0[3], ah1[3];
    #pragma unroll
    for (int kk = 0; kk < 3; kk++) {
        ah0[kk] = ldh(h16 + (rowbase + lmod) * 96 + kk * 32 + ldiv * 8);
        ah1[kk] = ldh(h16 + (rowbase + 16 + lmod) * 96 + kk * 32 + ldiv * 8);
    }

    // Q projection (sqrt(D) folded)
    f32x4 qa0[6] = {}, qa1[6] = {};
    #pragma unroll
    for (int kk = 0; kk < 3; kk++)
        #pragma unroll
        for (int n = 0; n < 6; n++) {
            f16x8 bf = ldh(wqS + (size_t)(((hd * 6 + n) * 3 + kk) * 64) * 8 + lane * 8);
            qa0[n] = __builtin_amdgcn_mfma_f32_16x16x32_f16(ah0[kk], bf, qa0[n], 0, 0, 0);
            qa1[n] = __builtin_amdgcn_mfma_f32_16x16x32_f16(ah1[kk], bf, qa1[n], 0, 0, 0);
        }
    #pragma unroll
    for (int n = 0; n < 6; n++)
        #pragma unroll
        for (int r = 0; r < 4; r++) {
            stg[(ldiv * 4 + r) * 104 + n * 16 + lmod] = f2h(qa0[n][r]);
            stg[(16 + ldiv * 4 + r) * 104 + n * 16 + lmod] = f2h(qa1[n][r]);
        }
    f16x8 aq0[3], aq1[3];
    #pragma unroll
    for (int kk = 0; kk < 3; kk++) {
        aq0[kk] = ldh(&stg[lmod * 104 + kk * 32 + ldiv * 8]);
        aq1[kk] = ldh(&stg[(16 + lmod) * 104 + kk * 32 + ldiv * 8]);
    }

    const us* Kh = Kall + (size_t)hd * NTOT + (size_t)b * 24 * 1536;
    const us* Vh = Vall + (size_t)hd * NTOT + (size_t)b * 36 * 1024;

    f32x4 oacc0[6] = {}, oacc1[6] = {};
    f32x4 m0v = {-1e30f, -1e30f, -1e30f, -1e30f}, m1v = m0v;
    f32x4 l0v = {}, l1v = {};

    for (int c = 0; c < 6; c++) {
        f32x4 s0[4] = {}, s1[4] = {};
        #pragma unroll
        for (int nt = 0; nt < 4; nt++)
            #pragma unroll
            for (int kk = 0; kk < 3; kk++) {
                f16x8 bf = ldh(Kh + (size_t)((c * 4 + nt) * 3 + kk) * 512 + lane * 8);
                s0[nt] = __builtin_amdgcn_mfma_f32_16x16x32_f16(aq0[kk], bf, s0[nt], 0, 0, 0);
                s1[nt] = __builtin_amdgcn_mfma_f32_16x16x32_f16(aq1[kk], bf, s1[nt], 0, 0, 0);
            }

        // online softmax, m-tile 0 (P staged into stg rows 0-15, stride 72)
        #pragma unroll
        for (int r = 0; r < 4; r++) {
            float cm = fmaxf(fmaxf(s0[0][r], s0[1][r]), fmaxf(s0[2][r], s0[3][r]));
            cm = fmaxf(cm, __shfl_xor(cm, 1));
            cm = fmaxf(cm, __shfl_xor(cm, 2));
            cm = fmaxf(cm, __shfl_xor(cm, 4));
            cm = fmaxf(cm, __shfl_xor(cm, 8));
            float mn = fmaxf(m0v[r], cm);
            float scl = __expf(m0v[r] - mn);
            m0v[r] = mn;
            float ssum = 0.f;
            #pragma unroll
            for (int nt = 0; nt < 4; nt++) {
                float pv = __expf(s0[nt][r] - mn);
                s0[nt][r] = pv;
                ssum += pv;
            }
            ssum += __shfl_xor(ssum, 1);
            ssum += __shfl_xor(ssum, 2);
            ssum += __shfl_xor(ssum, 4);
            ssum += __shfl_xor(ssum, 8);
            l0v[r] = l0v[r] * scl + ssum;
            #pragma unroll
            for (int n = 0; n < 6; n++) oacc0[n][r] *= scl;
            #pragma unroll
            for (int nt = 0; nt < 4; nt++)
                stg[(ldiv * 4 + r) * 72 + nt * 16 + lmod] = f2h(s0[nt][r]);
        }
        // m-tile 1
        #pragma unroll
        for (int r = 0; r < 4; r++) {
            float cm = fmaxf(fmaxf(s1[0][r], s1[1][r]), fmaxf(s1[2][r], s1[3][r]));
            cm = fmaxf(cm, __shfl_xor(cm, 1));
            cm = fmaxf(cm, __shfl_xor(cm, 2));
            cm = fmaxf(cm, __shfl_xor(cm, 4));
            cm = fmaxf(cm, __shfl_xor(cm, 8));
            float mn = fmaxf(m1v[r], cm);
            float scl = __expf(m1v[r] - mn);
            m1v[r] = mn;
            float ssum = 0.f;
            #pragma unroll
            for (int nt = 0; nt < 4; nt++) {
                float pv = __expf(s1[nt][r] - mn);
                s1[nt][r] = pv;
                ssum += pv;
            }
            ssum += __shfl_xor(ssum, 1);
            ssum += __shfl_xor(ssum, 2);
            ssum += __shfl_xor(ssum, 4);
            ssum += __shfl_xor(ssum, 8);
            l1v[r] = l1v[r] * scl + ssum;
            #pragma unroll
            for (int n = 0; n < 6; n++) oacc1[n][r] *= scl;
            #pragma unroll
            for (int nt = 0; nt < 4; nt++)
                stg[(16 + ldiv * 4 + r) * 72 + nt * 16 + lmod] = f2h(s1[nt][r]);
        }

        // PV; V B-frags reused across both m-tiles
        #pragma unroll
        for (int kk = 0; kk < 2; kk++) {
            f16x8 pf0 = ldh(&stg[lmod * 72 + kk * 32 + ldiv * 8]);
            f16x8 pf1 = ldh(&stg[(16 + lmod) * 72 + kk * 32 + ldiv * 8]);
            #pragma unroll
            for (int n = 0; n < 6; n++) {
                f16x8 bf = ldh(Vh + (size_t)((n * 6 + c) * 2 + kk) * 512 + lane * 8);
                oacc0[n] = __builtin_amdgcn_mfma_f32_16x16x32_f16(pf0, bf, oacc0[n], 0, 0, 0);
                oacc1[n] = __builtin_amdgcn_mfma_f32_16x16x32_f16(pf1, bf, oacc1[n], 0, 0, 0);
            }
        }
    }

    // finalize
    us* xp = xpart + (size_t)hd * NTOT;
    #pragma unroll
    for (int r = 0; r < 4; r++) {
        float inv0 = 1.f / l0v[r];
        float inv1 = 1.f / l1v[r];
        #pragma unroll
        for (int n = 0; n < 6; n++) {
            xp[(rowbase + ldiv * 4 + r) * 96 + n * 16 + lmod] = f2h(oacc0[n][r] * inv0);
            xp[(rowbase + 16 + ldiv * 4 + r) * 96 + n * 16 + lmod] = f2h(oacc1[n][r] * inv1);
        }
    }
}

// ---------------- fused head-reduce + LN + FFN ----------------
// x' = x + sum_h xpart[h]; out = x' + sigmoid(LN(x')@w1+b1)@w2+b2
__global__ void ffn_ln(const float* __restrict__ x, const us* __restrict__ xpart,
                       const float* __restrict__ gln, const float* __restrict__ bln,
                       const us* __restrict__ w1T, const float* __restrict__ b1,
                       const us* __restrict__ w2Tp, const float* __restrict__ b2,
                       float* __restrict__ out) {
    __shared__ float xf[64 * 96];
    __shared__ us lnb[64 * 104];
    __shared__ us mid[64 * 72];
    int tid = threadIdx.x, wave = tid >> 6, lane = tid & 63;
    int lmod = lane & 15, ldiv = lane >> 4, m0 = wave * 16;
    int row0 = blockIdx.x * 64;

    for (int i = wave; i < 64; i += 4) {
        size_t ro = (size_t)(row0 + i) * 96;
        float v0 = x[ro + lane];
        float v1 = (lane < 32) ? x[ro + 64 + lane] : 0.f;
        #pragma unroll
        for (int h = 0; h < H; h++) {
            const us* xp = xpart + (size_t)h * NTOT + ro;
            v0 += (float)__builtin_bit_cast(_Float16, xp[lane]);
            if (lane < 32) v1 += (float)__builtin_bit_cast(_Float16, xp[64 + lane]);
        }
        xf[i * 96 + lane] = v0;
        if (lane < 32) xf[i * 96 + 64 + lane] = v1;
        float sm = v0 + v1, q = v0 * v0 + v1 * v1;
        for (int off = 32; off > 0; off >>= 1) {
            sm += __shfl_xor(sm, off);
            q += __shfl_xor(q, off);
        }
        float mean = sm * (1.0f / D);
        float var = q * (1.0f / D) - mean * mean;
        float rstd = rsqrtf(var + 1e-5f);
        lnb[i * 104 + lane] = f2h((v0 - mean) * rstd * gln[lane] + bln[lane]);
        if (lane < 32)
            lnb[i * 104 + 64 + lane] = f2h((v1 - mean) * rstd * gln[lane + 64] + bln[lane + 64]);
    }
    __syncthreads();

    f32x4 a3[3] = {};
    #pragma unroll
    for (int kk = 0; kk < 3; kk++) {
        f16x8 af = ldh(&lnb[(m0 + lmod) * 104 + kk * 32 + ldiv * 8]);
        #pragma unroll
        for (int n = 0; n < 3; n++) {
            f16x8 bf = ldh(w1T + (size_t)(n * 16 + lmod) * 96 + kk * 32 + ldiv * 8);
            a3[n] = __builtin_amdgcn_mfma_f32_16x16x32_f16(af, bf, a3[n], 0, 0, 0);
        }
    }
    #pragma unroll
    for (int n = 0; n < 3; n++) {
        float bv = b1[n * 16 + lmod];
        #pragma unroll
        for (int r = 0; r < 4; r++) {
            float v = a3[n][r] + bv;
            mid[(m0 + ldiv * 4 + r) * 72 + n * 16 + lmod] = f2h(1.f / (1.f + __expf(-v)));
        }
    }
    #pragma unroll
    for (int r = 0; r < 4; r++) mid[(m0 + ldiv * 4 + r) * 72 + 48 + lmod] = 0;
    __syncthreads();

    f32x4 a6[6] = {};
    #pragma unroll
    for (int kk = 0; kk < 2; kk++) {
        f16x8 af = ldh(&mid[(m0 + lmod) * 72 + kk * 32 + ldiv * 8]);
        #pragma unroll
        for (int n = 0; n < 6; n++) {
            f16x8 bf = ldh(w2Tp + (size_t)(n * 16 + lmod) * 64 + kk * 32 + ldiv * 8);
            a6[n] = __builtin_amdgcn_mfma_f32_16x16x32_f16(af, bf, a6[n], 0, 0, 0);
        }
    }
    #pragma unroll
    for (int n = 0; n < 6; n++) {
        int o = n * 16 + lmod;
        float bv = b2[o];
        #pragma unroll
        for (int r = 0; r < 4; r++) {
            int sr = m0 + ldiv * 4 + r;
            out[(size_t)(row0 + sr) * 96 + o] = xf[sr * 96 + o] + a6[n][r] + bv;
        }
    }
}

extern "C" void kernel_launch(void* const* d_in, const int* in_sizes, int n_in,
                              void* d_out, int out_size, void* d_ws, size_t ws_size,
                              hipStream_t stream) {
    const float* in   = (const float*)d_in[0];
    const float* cdw  = (const float*)d_in[2];
    const float* cdwb = (const float*)d_in[3];
    const float* cpw  = (const float*)d_in[4];
    const float* cpwb = (const float*)d_in[5];
    const float* WQ   = (const float*)d_in[6];
    const float* WK   = (const float*)d_in[7];
    const float* WV   = (const float*)d_in[8];
    const float* WO   = (const float*)d_in[9];
    const float* w1   = (const float*)d_in[10];
    const float* b1   = (const float*)d_in[11];
    const float* w2   = (const float*)d_in[12];
    const float* b2   = (const float*)d_in[13];
    const float* lng  = (const float*)d_in[14];
    const float* lnb  = (const float*)d_in[15];
    float* out = (float*)d_out;
    float* ws = (float*)d_ws;

    float* x   = ws;
    float* pe  = x + NTOT;
    float* x2  = pe + S * D;
    us* h16    = (us*)(x2 + NTOT);
    us* Kall   = h16 + NTOT;               // [H][B][24][3][64][8]
    us* Vall   = Kall + (size_t)H * NTOT;  // [H][B][6][6][2][64][8]
    us* xpart  = Vall + (size_t)H * NTOT;  // [H][ROWS][96]
    us* wqS    = xpart + (size_t)H * NTOT;
    us* wkT    = wqS + H * D * D;
    us* wvoT   = wkT + H * D * D;
    us* pw16   = wvoT + H * D * D;
    us* w1T    = pw16 + L * D * D;
    us* w2Tp   = w1T + 48 * 96;
    // total ~= 161 MB (< 256 MB ws)

    pe_kernel<<<(S * D + 255) / 256, 256, 0, stream>>>(pe);
    prep_w<<<(H * D * D + 255) / 256, 256, 0, stream>>>(WQ, WK, cpw, w1, w2,
                                                        wqS, wkT, pw16, w1T, w2Tp);
    prep_wvo<<<H * 6, 256, 0, stream>>>(WV, WO, wvoT);

    // layer 0 fuses embed (in*sqrtD + pe); ping-pong thereafter; result ends in x
    conv_fused_t<1><<<ROWS / 64, 256, 0, stream>>>(nullptr, in, pe, x2, lng, lnb,
                                                   cdw, cdwb, pw16, cpwb);
    for (int i = 1; i < L; i++) {
        const float* xi = (i & 1) ? x2 : x;
        float* xo = (i & 1) ? x : x2;
        conv_fused_t<0><<<ROWS / 64, 256, 0, stream>>>(xi, nullptr, nullptr, xo,
                                                       lng + i * D, lnb + i * D,
                                                       cdw + i * D * KW, cdwb + i * D,
                                                       pw16 + i * D * D, cpwb + i * D);
    }

    ln16h_kernel<<<ROWS / 4, 256, 0, stream>>>(x, lng + L * D, lnb + L * D, h16);
    proj_all<<<dim3(ROWS / 64, H), 256, 0, stream>>>(h16, wkT, wvoT, Kall, Vall);
    attn_h32<<<B * 12 * H, 64, 0, stream>>>(h16, wqS, Kall, Vall, xpart);

    ffn_ln<<<ROWS / 64, 256, 0, stream>>>(x, xpart, lng + (L + 1) * D, lnb + (L + 1) * D,
                                          w1T, b1, w2Tp, b2, out);
}

// Round 11
// 337.817 us; speedup vs baseline: 1.5486x; 1.0243x over previous
//
#include <hip/hip_runtime.h>
#include <math.h>

// EmbeddingEncoder: B=128, S=384, D=96, H=4, K=7, L=4.
// Round 10: two-pass softmax attention (recompute QK^T; zero rescale VALU),
// producer-side LN in conv chain (dw reads LN'd f16 halo from global).

constexpr int B = 128;
constexpr int S = 384;
constexpr int D = 96;
constexpr int H = 4;
constexpr int KW = 7;
constexpr int L = 4;
constexpr int ROWS = B * S;                      // 49152
constexpr long long NTOT = (long long)ROWS * D;  // 4718592
constexpr float SQRTD = 9.797958971132712f;

typedef _Float16 f16x8 __attribute__((ext_vector_type(8)));
typedef float f32x4 __attribute__((ext_vector_type(4)));
typedef unsigned short us;
typedef unsigned short us8 __attribute__((ext_vector_type(8)));

__device__ __forceinline__ us f2h(float f) {
    _Float16 h = (_Float16)f;
    return __builtin_bit_cast(us, h);
}
__device__ __forceinline__ f16x8 ldh(const us* p) {
    return *reinterpret_cast<const f16x8*>(p);
}

// ---------------- positional encoding ----------------
__global__ void pe_kernel(float* __restrict__ pe) {
    int idx = blockIdx.x * 256 + threadIdx.x;
    if (idx >= S * D) return;
    int s = idx / D, c = idx - s * D;
    int j = c >> 1;
    float expo = (c & 1) ? (4.0f * j + 2.0f) / 96.0f : (4.0f * j) / 96.0f;
    float freq = expf(-expo * logf(10000.0f));
    float ang = (float)s * freq;
    pe[idx] = (c & 1) ? cosf(ang) : sinf(ang);
}

// ---------------- weight prep ----------------
__global__ void prep_w(const float* __restrict__ WQ, const float* __restrict__ WK,
                       const float* __restrict__ cpw, const float* __restrict__ w1,
                       const float* __restrict__ w2,
                       us* __restrict__ wqS, us* __restrict__ wkT, us* __restrict__ pw16,
                       us* __restrict__ w1T, us* __restrict__ w2Tp) {
    int idx = blockIdx.x * 256 + threadIdx.x;
    if (idx >= H * D * D) return;  // 36864
    int h = idx / (D * D), rem = idx - h * (D * D);
    int d = rem / D, e = rem - d * D;
    int n = e >> 4, lmod = e & 15, kk = d >> 5, ldiv = (d >> 3) & 3, j = d & 7;
    wqS[(size_t)(((h * 6 + n) * 3 + kk) * 64 + ldiv * 16 + lmod) * 8 + j] = f2h(WQ[idx] * SQRTD);
    wkT[(size_t)h * D * D + e * D + d] = f2h(WK[idx]);
    pw16[idx] = f2h(cpw[idx]);  // L*D*D == 36864
    if (idx < 48 * 96) {
        int m = idx / 96, c = idx - m * 96;
        w1T[idx] = f2h(w1[c * 48 + m]);
    }
    if (idx < 96 * 64) {
        int o = idx / 64, m = idx - o * 64;
        w2Tp[idx] = (m < 48) ? f2h(w2[m * 96 + o]) : (us)0;
    }
}

// ---------------- WVO_h = WV_h @ WO_h, stored transposed [h][o][d] ----------------
__global__ void prep_wvo(const float* __restrict__ WV, const float* __restrict__ WO,
                         us* __restrict__ wvoT) {
    int blk = blockIdx.x;  // 24 = H * 6
    int h = blk / 6, ot = blk - h * 6;
    int tid = threadIdx.x;
    const float* wv = WV + (size_t)h * D * D;
    const float* wo = WO + (size_t)h * D * D;
    for (int i = tid; i < 16 * 96; i += 256) {
        int o = ot * 16 + i / 96, d = i - (i / 96) * 96;
        float acc = 0.f;
        for (int e = 0; e < 96; e++) acc += wv[d * 96 + e] * wo[e * 96 + o];
        wvoT[(size_t)h * D * D + o * 96 + d] = f2h(acc);
    }
}

// ---------------- prologue: x = in*sqrtD + pe; ln0 = LN(x)*g+b (f16) ----------------
__global__ void embed_ln(const float* __restrict__ in, const float* __restrict__ pe,
                         const float* __restrict__ gln, const float* __restrict__ bln,
                         float* __restrict__ x, us* __restrict__ lnout) {
    int wave = threadIdx.x >> 6;
    int lane = threadIdx.x & 63;
    int row = blockIdx.x * 4 + wave;
    if (row >= ROWS) return;
    int s = row % S;
    size_t ro = (size_t)row * D;
    float v0 = in[ro + lane] * SQRTD + pe[s * 96 + lane];
    float v1 = (lane < 32) ? in[ro + 64 + lane] * SQRTD + pe[s * 96 + 64 + lane] : 0.f;
    x[ro + lane] = v0;
    if (lane < 32) x[ro + 64 + lane] = v1;
    float sm = v0 + v1, q = v0 * v0 + v1 * v1;
    for (int off = 32; off > 0; off >>= 1) {
        sm += __shfl_xor(sm, off);
        q += __shfl_xor(q, off);
    }
    float mean = sm * (1.0f / D);
    float var = q * (1.0f / D) - mean * mean;
    float rstd = rsqrtf(var + 1e-5f);
    lnout[ro + lane] = f2h((v0 - mean) * rstd * gln[lane] + bln[lane]);
    if (lane < 32)
        lnout[ro + 64 + lane] = f2h((v1 - mean) * rstd * gln[lane + 64] + bln[lane + 64]);
}

// ---------------- conv layer: dw(lnin f16 global) -> pw MFMA -> out = xin + relu;
//                  then produce LN_next(out) f16 in-register (no extra pass) ----------------
__global__ void conv2(const float* __restrict__ xin, const us* __restrict__ lnin,
                      float* __restrict__ xout, us* __restrict__ lnout,
                      const float* __restrict__ dwW, const float* __restrict__ dwB,
                      const us* __restrict__ pwW, const float* __restrict__ pwb,
                      const float* __restrict__ gnext, const float* __restrict__ bnext) {
    __shared__ us dwb_s[64 * 104];
    __shared__ float lw[96 * 8];
    int tid = threadIdx.x;
    int wave = tid >> 6, lane = tid & 63;
    int r0 = blockIdx.x * 64;
    int b = r0 / S, s0 = r0 % S;

    for (int i = tid; i < 96 * KW; i += 256) lw[(i / KW) * 8 + (i % KW)] = dwW[i];
    __syncthreads();

    // depthwise conv from LN'd f16 (halo straight from global; zero outside sequence)
    for (int u = tid; u < 768; u += 256) {
        int j = u / 12, c0 = (u - (u / 12) * 12) * 8;
        float acc[8];
        #pragma unroll
        for (int j2 = 0; j2 < 8; j2++) acc[j2] = dwB[c0 + j2];
        #pragma unroll
        for (int k = 0; k < KW; k++) {
            int ss = s0 + j + k - 3;
            if ((unsigned)ss < (unsigned)S) {
                f16x8 v = ldh(lnin + ((size_t)b * S + ss) * 96 + c0);
                #pragma unroll
                for (int j2 = 0; j2 < 8; j2++) acc[j2] += (float)v[j2] * lw[(c0 + j2) * 8 + k];
            }
        }
        us8 o;
        #pragma unroll
        for (int j2 = 0; j2 < 8; j2++) o[j2] = f2h(acc[j2]);
        *reinterpret_cast<us8*>(&dwb_s[j * 104 + c0]) = o;
    }
    __syncthreads();

    // pointwise MFMA
    int lmod = lane & 15, ldiv = lane >> 4, m0 = wave * 16;
    f32x4 acc[6] = {};
    #pragma unroll
    for (int kk = 0; kk < 3; kk++) {
        f16x8 af = ldh(&dwb_s[(m0 + lmod) * 104 + kk * 32 + ldiv * 8]);
        #pragma unroll
        for (int n = 0; n < 6; n++) {
            f16x8 bf = ldh(pwW + (size_t)(n * 16 + lmod) * 96 + kk * 32 + ldiv * 8);
            acc[n] = __builtin_amdgcn_mfma_f32_16x16x32_f16(af, bf, acc[n], 0, 0, 0);
        }
    }

    // residual + relu, then in-register row LN for the NEXT stage
    float gv[6], bv2[6], pb[6];
    #pragma unroll
    for (int n = 0; n < 6; n++) {
        int o = n * 16 + lmod;
        gv[n] = gnext[o];
        bv2[n] = bnext[o];
        pb[n] = pwb[o];
    }
    #pragma unroll
    for (int n = 0; n < 6; n++) {
        #pragma unroll
        for (int r = 0; r < 4; r++) {
            size_t row = (size_t)r0 + m0 + ldiv * 4 + r;
            acc[n][r] = xin[row * 96 + n * 16 + lmod] + fmaxf(acc[n][r] + pb[n], 0.f);
        }
    }
    #pragma unroll
    for (int r = 0; r < 4; r++) {
        float sm = 0.f, qq = 0.f;
        #pragma unroll
        for (int n = 0; n < 6; n++) {
            sm += acc[n][r];
            qq += acc[n][r] * acc[n][r];
        }
        #pragma unroll
        for (int st = 1; st <= 8; st <<= 1) {
            sm += __shfl_xor(sm, st);
            qq += __shfl_xor(qq, st);
        }
        float mean = sm * (1.0f / D);
        float var = qq * (1.0f / D) - mean * mean;
        float rstd = rsqrtf(var + 1e-5f);
        size_t row = (size_t)r0 + m0 + ldiv * 4 + r;
        #pragma unroll
        for (int n = 0; n < 6; n++) {
            int o = n * 16 + lmod;
            xout[row * 96 + o] = acc[n][r];
            lnout[row * 96 + o] = f2h((acc[n][r] - mean) * rstd * gv[n] + bv2[n]);
        }
    }
}

// ---------------- K + V' projection -> fragment-order layouts ----------------
__global__ void proj_all(const us* __restrict__ h16, const us* __restrict__ wkT,
                         const us* __restrict__ wvoT, us* __restrict__ Kall,
                         us* __restrict__ Vall) {
    __shared__ us stg[96 * 72];
    int hd = blockIdx.y;
    int tid = threadIdx.x;
    int wave = tid >> 6, lane = tid & 63, lmod = lane & 15, ldiv = lane >> 4;
    int row0 = blockIdx.x * 64, m0 = wave * 16;
    int b = row0 / S;

    f16x8 af[3];
    #pragma unroll
    for (int kk = 0; kk < 3; kk++)
        af[kk] = ldh(h16 + (size_t)(row0 + m0 + lmod) * 96 + kk * 32 + ldiv * 8);

    // ---- K ----
    {
        const us* W = wkT + (size_t)hd * D * D;
        f32x4 acc[6] = {};
        #pragma unroll
        for (int kk = 0; kk < 3; kk++)
            #pragma unroll
            for (int n = 0; n < 6; n++) {
                f16x8 bf = ldh(W + (size_t)(n * 16 + lmod) * 96 + kk * 32 + ldiv * 8);
                acc[n] = __builtin_amdgcn_mfma_f32_16x16x32_f16(af[kk], bf, acc[n], 0, 0, 0);
            }
        us* kT = stg + wave * 1664;
        #pragma unroll
        for (int n = 0; n < 6; n++)
            #pragma unroll
            for (int r = 0; r < 4; r++)
                kT[(ldiv * 4 + r) * 104 + n * 16 + lmod] = f2h(acc[n][r]);
        int t0 = (row0 % S) / 16 + wave;
        us* dst = Kall + (size_t)hd * NTOT + ((size_t)(b * 24 + t0) * 3) * 512;
        #pragma unroll
        for (int kk = 0; kk < 3; kk++) {
            us8 v = *reinterpret_cast<const us8*>(&kT[lmod * 104 + kk * 32 + ldiv * 8]);
            *reinterpret_cast<us8*>(dst + kk * 512 + lane * 8) = v;
        }
    }
    __syncthreads();

    // ---- V' ----
    {
        const us* W = wvoT + (size_t)hd * D * D;
        f32x4 acc[6] = {};
        #pragma unroll
        for (int kk = 0; kk < 3; kk++)
            #pragma unroll
            for (int n = 0; n < 6; n++) {
                f16x8 bf = ldh(W + (size_t)(n * 16 + lmod) * 96 + kk * 32 + ldiv * 8);
                acc[n] = __builtin_amdgcn_mfma_f32_16x16x32_f16(af[kk], bf, acc[n], 0, 0, 0);
            }
        #pragma unroll
        for (int n = 0; n < 6; n++)
            #pragma unroll
            for (int r = 0; r < 4; r++)
                stg[(n * 16 + lmod) * 72 + m0 + ldiv * 4 + r] = f2h(acc[n][r]);
        __syncthreads();
        int cblk = (row0 % S) / 64;
        us* dsth = Vall + (size_t)hd * NTOT;
        #pragma unroll
        for (int n = 0; n < 6; n++)
            #pragma unroll
            for (int kk = 0; kk < 2; kk++) {
                us8 v =
                    *reinterpret_cast<const us8*>(&stg[(n * 16 + lmod) * 72 + kk * 32 + ldiv * 8]);
                *reinterpret_cast<us8*>(
                    dsth + ((size_t)((b * 6 + n) * 6 + cblk) * 2 + kk) * 512 + lane * 8) = v;
            }
    }
}

// ---------------- two-pass attention: one wave, 32 q-rows, one head -> xpart[hd] ----------------
// Pass 1: QK^T MFMA, running row max in regs (no trees). Tree once.
// Pass 2: recompute QK^T, P = exp(s - M), l accumulated in regs, PV per chunk. Tree once.
__global__ __launch_bounds__(64, 3) void attn_2p(const us* __restrict__ h16,
                                                 const us* __restrict__ wqS,
                                                 const us* __restrict__ Kall,
                                                 const us* __restrict__ Vall,
                                                 us* __restrict__ xpart) {
    __shared__ us stg[32 * 104];
    int lane = threadIdx.x;
    int lmod = lane & 15, ldiv = lane >> 4;
    int p = blockIdx.x;
    int gl = (p & 7) * 768 + (p >> 3);  // 6144 = 8 * 768, XCD-chunked
    int t = gl % 12;
    int bh = gl / 12;
    int b = bh >> 2, hd = bh & 3;
    size_t rowbase = (size_t)b * S + t * 32;

    // h A-frags for both m-tiles
    f16x8 ah0[3], ah1[3];
    #pragma unroll
    for (int kk = 0; kk < 3; kk++) {
        ah0[kk] = ldh(h16 + (rowbase + lmod) * 96 + kk * 32 + ldiv * 8);
        ah1[kk] = ldh(h16 + (rowbase + 16 + lmod) * 96 + kk * 32 + ldiv * 8);
    }

    // Q projection (sqrt(D) folded)
    f32x4 qa0[6] = {}, qa1[6] = {};
    #pragma unroll
    for (int kk = 0; kk < 3; kk++)
        #pragma unroll
        for (int n = 0; n < 6; n++) {
            f16x8 bf = ldh(wqS + (size_t)(((hd * 6 + n) * 3 + kk) * 64) * 8 + lane * 8);
            qa0[n] = __builtin_amdgcn_mfma_f32_16x16x32_f16(ah0[kk], bf, qa0[n], 0, 0, 0);
            qa1[n] = __builtin_amdgcn_mfma_f32_16x16x32_f16(ah1[kk], bf, qa1[n], 0, 0, 0);
        }
    #pragma unroll
    for (int n = 0; n < 6; n++)
        #pragma unroll
        for (int r = 0; r < 4; r++) {
            stg[(ldiv * 4 + r) * 104 + n * 16 + lmod] = f2h(qa0[n][r]);
            stg[(16 + ldiv * 4 + r) * 104 + n * 16 + lmod] = f2h(qa1[n][r]);
        }
    f16x8 aq0[3], aq1[3];
    #pragma unroll
    for (int kk = 0; kk < 3; kk++) {
        aq0[kk] = ldh(&stg[lmod * 104 + kk * 32 + ldiv * 8]);
        aq1[kk] = ldh(&stg[(16 + lmod) * 104 + kk * 32 + ldiv * 8]);
    }

    const us* Kh = Kall + (size_t)hd * NTOT + (size_t)b * 24 * 1536;
    const us* Vh = Vall + (size_t)hd * NTOT + (size_t)b * 36 * 1024;

    // ---- pass 1: row max ----
    f32x4 mx0 = {-1e30f, -1e30f, -1e30f, -1e30f}, mx1 = mx0;
    for (int c = 0; c < 6; c++) {
        f32x4 s0[4] = {}, s1[4] = {};
        __builtin_amdgcn_s_setprio(1);
        #pragma unroll
        for (int nt = 0; nt < 4; nt++)
            #pragma unroll
            for (int kk = 0; kk < 3; kk++) {
                f16x8 bf = ldh(Kh + (size_t)((c * 4 + nt) * 3 + kk) * 512 + lane * 8);
                s0[nt] = __builtin_amdgcn_mfma_f32_16x16x32_f16(aq0[kk], bf, s0[nt], 0, 0, 0);
                s1[nt] = __builtin_amdgcn_mfma_f32_16x16x32_f16(aq1[kk], bf, s1[nt], 0, 0, 0);
            }
        __builtin_amdgcn_s_setprio(0);
        #pragma unroll
        for (int nt = 0; nt < 4; nt++)
            #pragma unroll
            for (int r = 0; r < 4; r++) {
                mx0[r] = fmaxf(mx0[r], s0[nt][r]);
                mx1[r] = fmaxf(mx1[r], s1[nt][r]);
            }
    }
    #pragma unroll
    for (int st = 1; st <= 8; st <<= 1)
        #pragma unroll
        for (int r = 0; r < 4; r++) {
            mx0[r] = fmaxf(mx0[r], __shfl_xor(mx0[r], st));
            mx1[r] = fmaxf(mx1[r], __shfl_xor(mx1[r], st));
        }

    // ---- pass 2: recompute scores, exp, accumulate l, PV ----
    f32x4 oacc0[6] = {}, oacc1[6] = {};
    f32x4 l0v = {}, l1v = {};
    for (int c = 0; c < 6; c++) {
        f32x4 s0[4] = {}, s1[4] = {};
        __builtin_amdgcn_s_setprio(1);
        #pragma unroll
        for (int nt = 0; nt < 4; nt++)
            #pragma unroll
            for (int kk = 0; kk < 3; kk++) {
                f16x8 bf = ldh(Kh + (size_t)((c * 4 + nt) * 3 + kk) * 512 + lane * 8);
                s0[nt] = __builtin_amdgcn_mfma_f32_16x16x32_f16(aq0[kk], bf, s0[nt], 0, 0, 0);
                s1[nt] = __builtin_amdgcn_mfma_f32_16x16x32_f16(aq1[kk], bf, s1[nt], 0, 0, 0);
            }
        __builtin_amdgcn_s_setprio(0);
        #pragma unroll
        for (int nt = 0; nt < 4; nt++)
            #pragma unroll
            for (int r = 0; r < 4; r++) {
                float p0 = __expf(s0[nt][r] - mx0[r]);
                float p1 = __expf(s1[nt][r] - mx1[r]);
                l0v[r] += p0;
                l1v[r] += p1;
                stg[(ldiv * 4 + r) * 72 + nt * 16 + lmod] = f2h(p0);
                stg[(16 + ldiv * 4 + r) * 72 + nt * 16 + lmod] = f2h(p1);
            }
        __builtin_amdgcn_s_setprio(1);
        #pragma unroll
        for (int kk = 0; kk < 2; kk++) {
            f16x8 pf0 = ldh(&stg[lmod * 72 + kk * 32 + ldiv * 8]);
            f16x8 pf1 = ldh(&stg[(16 + lmod) * 72 + kk * 32 + ldiv * 8]);
            #pragma unroll
            for (int n = 0; n < 6; n++) {
                f16x8 bf = ldh(Vh + (size_t)((n * 6 + c) * 2 + kk) * 512 + lane * 8);
                oacc0[n] = __builtin_amdgcn_mfma_f32_16x16x32_f16(pf0, bf, oacc0[n], 0, 0, 0);
                oacc1[n] = __builtin_amdgcn_mfma_f32_16x16x32_f16(pf1, bf, oacc1[n], 0, 0, 0);
            }
        }
        __builtin_amdgcn_s_setprio(0);
    }
    #pragma unroll
    for (int st = 1; st <= 8; st <<= 1)
        #pragma unroll
        for (int r = 0; r < 4; r++) {
            l0v[r] += __shfl_xor(l0v[r], st);
            l1v[r] += __shfl_xor(l1v[r], st);
        }

    // finalize
    us* xp = xpart + (size_t)hd * NTOT;
    #pragma unroll
    for (int r = 0; r < 4; r++) {
        float inv0 = 1.f / l0v[r];
        float inv1 = 1.f / l1v[r];
        #pragma unroll
        for (int n = 0; n < 6; n++) {
            xp[(rowbase + ldiv * 4 + r) * 96 + n * 16 + lmod] = f2h(oacc0[n][r] * inv0);
            xp[(rowbase + 16 + ldiv * 4 + r) * 96 + n * 16 + lmod] = f2h(oacc1[n][r] * inv1);
        }
    }
}

// ---------------- fused head-reduce + LN + FFN ----------------
__global__ void ffn_ln(const float* __restrict__ x, const us* __restrict__ xpart,
                       const float* __restrict__ gln, const float* __restrict__ bln,
                       const us* __restrict__ w1T, const float* __restrict__ b1,
                       const us* __restrict__ w2Tp, const float* __restrict__ b2,
                       float* __restrict__ out) {
    __shared__ float xf[64 * 96];
    __shared__ us lnb[64 * 104];
    __shared__ us mid[64 * 72];
    int tid = threadIdx.x, wave = tid >> 6, lane = tid & 63;
    int lmod = lane & 15, ldiv = lane >> 4, m0 = wave * 16;
    int row0 = blockIdx.x * 64;

    for (int i = wave; i < 64; i += 4) {
        size_t ro = (size_t)(row0 + i) * 96;
        float v0 = x[ro + lane];
        float v1 = (lane < 32) ? x[ro + 64 + lane] : 0.f;
        #pragma unroll
        for (int h = 0; h < H; h++) {
            const us* xp = xpart + (size_t)h * NTOT + ro;
            v0 += (float)__builtin_bit_cast(_Float16, xp[lane]);
            if (lane < 32) v1 += (float)__builtin_bit_cast(_Float16, xp[64 + lane]);
        }
        xf[i * 96 + lane] = v0;
        if (lane < 32) xf[i * 96 + 64 + lane] = v1;
        float sm = v0 + v1, q = v0 * v0 + v1 * v1;
        for (int off = 32; off > 0; off >>= 1) {
            sm += __shfl_xor(sm, off);
            q += __shfl_xor(q, off);
        }
        float mean = sm * (1.0f / D);
        float var = q * (1.0f / D) - mean * mean;
        float rstd = rsqrtf(var + 1e-5f);
        lnb[i * 104 + lane] = f2h((v0 - mean) * rstd * gln[lane] + bln[lane]);
        if (lane < 32)
            lnb[i * 104 + 64 + lane] = f2h((v1 - mean) * rstd * gln[lane + 64] + bln[lane + 64]);
    }
    __syncthreads();

    f32x4 a3[3] = {};
    #pragma unroll
    for (int kk = 0; kk < 3; kk++) {
        f16x8 af = ldh(&lnb[(m0 + lmod) * 104 + kk * 32 + ldiv * 8]);
        #pragma unroll
        for (int n = 0; n < 3; n++) {
            f16x8 bf = ldh(w1T + (size_t)(n * 16 + lmod) * 96 + kk * 32 + ldiv * 8);
            a3[n] = __builtin_amdgcn_mfma_f32_16x16x32_f16(af, bf, a3[n], 0, 0, 0);
        }
    }
    #pragma unroll
    for (int n = 0; n < 3; n++) {
        float bv = b1[n * 16 + lmod];
        #pragma unroll
        for (int r = 0; r < 4; r++) {
            float v = a3[n][r] + bv;
            mid[(m0 + ldiv * 4 + r) * 72 + n * 16 + lmod] = f2h(1.f / (1.f + __expf(-v)));
        }
    }
    #pragma unroll
    for (int r = 0; r < 4; r++) mid[(m0 + ldiv * 4 + r) * 72 + 48 + lmod] = 0;
    __syncthreads();

    f32x4 a6[6] = {};
    #pragma unroll
    for (int kk = 0; kk < 2; kk++) {
        f16x8 af = ldh(&mid[(m0 + lmod) * 72 + kk * 32 + ldiv * 8]);
        #pragma unroll
        for (int n = 0; n < 6; n++) {
            f16x8 bf = ldh(w2Tp + (size_t)(n * 16 + lmod) * 64 + kk * 32 + ldiv * 8);
            a6[n] = __builtin_amdgcn_mfma_f32_16x16x32_f16(af, bf, a6[n], 0, 0, 0);
        }
    }
    #pragma unroll
    for (int n = 0; n < 6; n++) {
        int o = n * 16 + lmod;
        float bv = b2[o];
        #pragma unroll
        for (int r = 0; r < 4; r++) {
            int sr = m0 + ldiv * 4 + r;
            out[(size_t)(row0 + sr) * 96 + o] = xf[sr * 96 + o] + a6[n][r] + bv;
        }
    }
}

extern "C" void kernel_launch(void* const* d_in, const int* in_sizes, int n_in,
                              void* d_out, int out_size, void* d_ws, size_t ws_size,
                              hipStream_t stream) {
    const float* in   = (const float*)d_in[0];
    const float* cdw  = (const float*)d_in[2];
    const float* cdwb = (const float*)d_in[3];
    const float* cpw  = (const float*)d_in[4];
    const float* cpwb = (const float*)d_in[5];
    const float* WQ   = (const float*)d_in[6];
    const float* WK   = (const float*)d_in[7];
    const float* WV   = (const float*)d_in[8];
    const float* WO   = (const float*)d_in[9];
    const float* w1   = (const float*)d_in[10];
    const float* b1   = (const float*)d_in[11];
    const float* w2   = (const float*)d_in[12];
    const float* b2   = (const float*)d_in[13];
    const float* lng  = (const float*)d_in[14];
    const float* lnb  = (const float*)d_in[15];
    float* out = (float*)d_out;
    float* ws = (float*)d_ws;

    float* x   = ws;
    float* x2  = x + NTOT;
    float* pe  = x2 + NTOT;
    us* lnA    = (us*)(pe + S * D);
    us* lnB    = lnA + NTOT;
    us* Kall   = lnB + NTOT;               // [H][B][24][3][64][8]
    us* Vall   = Kall + (size_t)H * NTOT;  // [H][B][6][6][2][64][8]
    us* xpart  = Vall + (size_t)H * NTOT;  // [H][ROWS][96]
    us* wqS    = xpart + (size_t)H * NTOT;
    us* wkT    = wqS + H * D * D;
    us* wvoT   = wkT + H * D * D;
    us* pw16   = wvoT + H * D * D;
    us* w1T    = pw16 + L * D * D;
    us* w2Tp   = w1T + 48 * 96;
    // total ~= 170 MB (< 256 MB ws)

    pe_kernel<<<(S * D + 255) / 256, 256, 0, stream>>>(pe);
    prep_w<<<(H * D * D + 255) / 256, 256, 0, stream>>>(WQ, WK, cpw, w1, w2,
                                                        wqS, wkT, pw16, w1T, w2Tp);
    prep_wvo<<<H * 6, 256, 0, stream>>>(WV, WO, wvoT);

    // prologue: x0 + LN0
    embed_ln<<<ROWS / 4, 256, 0, stream>>>(in, pe, lng, lnb, x, lnA);

    // conv layers: (xin, lnin) -> (xout, lnout with NEXT stage's LN params)
    // layer i uses weights i and produces LN with lng[i+1]. After layer 3, x holds x4, lnA = h16.
    conv2<<<ROWS / 64, 256, 0, stream>>>(x, lnA, x2, lnB, cdw, cdwb, pw16, cpwb,
                                         lng + D, lnb + D);
    conv2<<<ROWS / 64, 256, 0, stream>>>(x2, lnB, x, lnA, cdw + D * KW, cdwb + D,
                                         pw16 + D * D, cpwb + D, lng + 2 * D, lnb + 2 * D);
    conv2<<<ROWS / 64, 256, 0, stream>>>(x, lnA, x2, lnB, cdw + 2 * D * KW, cdwb + 2 * D,
                                         pw16 + 2 * D * D, cpwb + 2 * D, lng + 3 * D,
                                         lnb + 3 * D);
    conv2<<<ROWS / 64, 256, 0, stream>>>(x2, lnB, x, lnA, cdw + 3 * D * KW, cdwb + 3 * D,
                                         pw16 + 3 * D * D, cpwb + 3 * D, lng + 4 * D,
                                         lnb + 4 * D);

    us* h16 = lnA;
    proj_all<<<dim3(ROWS / 64, H), 256, 0, stream>>>(h16, wkT, wvoT, Kall, Vall);
    attn_2p<<<B * 12 * H, 64, 0, stream>>>(h16, wqS, Kall, Vall, xpart);

    ffn_ln<<<ROWS / 64, 256, 0, stream>>>(x, xpart, lng + 5 * D, lnb + 5 * D,
                                          w1T, b1, w2Tp, b2, out);
}